// Round 10
// baseline (328.338 us; speedup 1.0000x reference)
//
#include <hip/hip_runtime.h>
#include <math.h>

#define WSG_STRIDE 260    // per-graph accum: 256 num + 1 denom (+pad)
#define ACC_STRIDE 257    // per-graph slots in LDS accumulator (fallback only)
#define MAXG 4            // fallback kernel only
#define NPB 64            // nodes per block (pool/fallback)
#define SG_STRIDE 27      // per-node S||G slot in LDS (26 used, odd -> no conflicts)

__device__ __forceinline__ float dot4f(float4 a, float4 b){
  return a.x*b.x + a.y*b.y + a.z*b.z + a.w*b.w;
}
__device__ __forceinline__ float gelu_exact(float x){
  return 0.5f*x*(1.0f+erff(x*0.70710678118654752440f));
}
__device__ __forceinline__ void mm44(float o[4][4], const float a[4][4], const float b[4][4]){
  #pragma unroll
  for (int i=0;i<4;++i){
    #pragma unroll
    for (int j=0;j<4;++j)
      o[i][j] = a[i][0]*b[0][j] + a[i][1]*b[1][j] + a[i][2]*b[2][j] + a[i][3]*b[3][j];
  }
}

template<int P,int Q,int K1,int K2>
__device__ __forceinline__ void jrot(float a[4][4], float V[4][4]){
  float apq = a[P][Q];
  if (fabsf(apq) > 1e-30f){
    float app=a[P][P], aqq=a[Q][Q];
    float tau=(aqq-app)/(2.0f*apq);
    float t=copysignf(1.0f,tau)/(fabsf(tau)+sqrtf(1.0f+tau*tau));
    float c=1.0f/sqrtf(1.0f+t*t), s=t*c;
    float a1p=a[K1][P], a1q=a[K1][Q];
    a[K1][P]=c*a1p-s*a1q; a[P][K1]=a[K1][P];
    a[K1][Q]=s*a1p+c*a1q; a[Q][K1]=a[K1][Q];
    float a2p=a[K2][P], a2q=a[K2][Q];
    a[K2][P]=c*a2p-s*a2q; a[P][K2]=a[K2][P];
    a[K2][Q]=s*a2p+c*a2q; a[Q][K2]=a[K2][Q];
    a[P][P]=app-t*apq; a[Q][Q]=aqq+t*apq; a[P][Q]=0.0f; a[Q][P]=0.0f;
    #pragma unroll
    for (int r=0;r<4;++r){ float vp=V[r][P], vq=V[r][Q]; V[r][P]=c*vp-s*vq; V[r][Q]=s*vp+c*vq; }
  }
}

__device__ __forceinline__ void jacobi4(float a[4][4], float V[4][4], int sweeps){
  #pragma unroll
  for (int i=0;i<4;++i){
    #pragma unroll
    for (int j=0;j<4;++j) V[i][j] = (i==j)?1.0f:0.0f;
  }
  for (int sw=0; sw<sweeps; ++sw){
    jrot<0,1,2,3>(a,V); jrot<0,2,1,3>(a,V); jrot<0,3,1,2>(a,V);
    jrot<1,2,0,3>(a,V); jrot<1,3,0,2>(a,V); jrot<2,3,0,1>(a,V);
  }
}

__device__ __forceinline__ float det4(const float V[4][4]){
  float s0 = V[0][0]*V[1][1] - V[0][1]*V[1][0];
  float s1 = V[0][0]*V[1][2] - V[0][2]*V[1][0];
  float s2 = V[0][0]*V[1][3] - V[0][3]*V[1][0];
  float s3 = V[0][1]*V[1][2] - V[0][2]*V[1][1];
  float s4 = V[0][1]*V[1][3] - V[0][3]*V[1][1];
  float s5 = V[0][2]*V[1][3] - V[0][3]*V[1][2];
  float c5 = V[2][2]*V[3][3] - V[2][3]*V[3][2];
  float c4 = V[2][1]*V[3][3] - V[2][3]*V[3][1];
  float c3 = V[2][1]*V[3][2] - V[2][2]*V[3][1];
  float c2 = V[2][0]*V[3][3] - V[2][3]*V[3][0];
  float c1 = V[2][0]*V[3][2] - V[2][2]*V[3][0];
  float c0 = V[2][0]*V[3][1] - V[2][1]*V[3][0];
  return s0*c5 - s1*c4 + s2*c3 + s3*c2 - s4*c1 + s5*c0;
}

// ============ device-side phase-2 body (shared) ============
__device__ __forceinline__ void phase2_body(const float Sd[10], const float Gd[16],
                                            float Wp[10], float Tout[16]){
  float a00=Sd[0]+1e-4f, a01=Sd[1], a02=Sd[2], a03=Sd[3];
  float a11=Sd[4]+1e-4f, a12=Sd[5], a13=Sd[6];
  float a22=Sd[7]+1e-4f, a23=Sd[8], a33=Sd[9]+1e-4f;
  float Gm[4][4];
  #pragma unroll
  for (int d=0;d<4;++d){
    #pragma unroll
    for (int f=0;f<4;++f) Gm[d][f]=Gd[4*d+f];
  }
  float cs = 0.4f*(a00+a11+a22+a33);
  float rc = 1.0f/cs;
  float Y[4][4], Z[4][4];
  Y[0][0]=a00*rc; Y[0][1]=Y[1][0]=a01*rc; Y[0][2]=Y[2][0]=a02*rc; Y[0][3]=Y[3][0]=a03*rc;
  Y[1][1]=a11*rc; Y[1][2]=Y[2][1]=a12*rc; Y[1][3]=Y[3][1]=a13*rc;
  Y[2][2]=a22*rc; Y[2][3]=Y[3][2]=a23*rc; Y[3][3]=a33*rc;
  #pragma unroll
  for (int i=0;i<4;++i){
    #pragma unroll
    for (int j=0;j<4;++j) Z[i][j]=(i==j)?1.0f:0.0f;
  }
  #pragma unroll
  for (int it=0; it<8; ++it){
    float P[4][4], Y2[4][4], Z2[4][4];
    mm44(P, Z, Y);
    #pragma unroll
    for (int i=0;i<4;++i){
      #pragma unroll
      for (int j=0;j<4;++j) P[i][j] = (i==j) ? 1.5f-0.5f*P[i][j] : -0.5f*P[i][j];
    }
    mm44(Y2, Y, P);
    mm44(Z2, P, Z);
    #pragma unroll
    for (int i=0;i<4;++i){
      #pragma unroll
      for (int j=0;j<4;++j){ Y[i][j]=Y2[i][j]; Z[i][j]=Z2[i][j]; }
    }
  }
  float rsc = rsqrtf(cs);
  float Wm[4][4];
  #pragma unroll
  for (int i=0;i<4;++i){
    #pragma unroll
    for (int j=0;j<4;++j) Wm[i][j] = Z[i][j]*rsc;
  }
  Wp[0]=Wm[0][0]; Wp[1]=Wm[0][1]; Wp[2]=Wm[0][2]; Wp[3]=Wm[0][3];
  Wp[4]=Wm[1][1]; Wp[5]=Wm[1][2]; Wp[6]=Wm[1][3];
  Wp[7]=Wm[2][2]; Wp[8]=Wm[2][3]; Wp[9]=Wm[3][3];
  float M[4][4];
  mm44(M, Gm, Wm);
  float A2[4][4];
  #pragma unroll
  for (int i=0;i<4;++i){
    #pragma unroll
    for (int j=0;j<4;++j)
      A2[i][j] = M[0][i]*M[0][j] + M[1][i]*M[1][j] + M[2][i]*M[2][j] + M[3][i]*M[3][j];
  }
  float V2[4][4];
  jacobi4(A2, V2, 4);
  float mu[4];
  #pragma unroll
  for (int i=0;i<4;++i) mu[i]=A2[i][i];
  #define CSW(I,J) if (mu[I] < mu[J]) { float tw; \
    tw=mu[I]; mu[I]=mu[J]; mu[J]=tw; \
    tw=V2[0][I]; V2[0][I]=V2[0][J]; V2[0][J]=tw; \
    tw=V2[1][I]; V2[1][I]=V2[1][J]; V2[1][J]=tw; \
    tw=V2[2][I]; V2[2][I]=V2[2][J]; V2[2][J]=tw; \
    tw=V2[3][I]; V2[3][I]=V2[3][J]; V2[3][J]=tw; }
  CSW(0,1) CSW(2,3) CSW(0,2) CSW(1,3) CSW(1,2)
  #undef CSW
  float u0[4],u1[4],u2[4];
  #pragma unroll
  for (int d=0;d<4;++d){
    u0[d]=M[d][0]*V2[0][0]+M[d][1]*V2[1][0]+M[d][2]*V2[2][0]+M[d][3]*V2[3][0];
    u1[d]=M[d][0]*V2[0][1]+M[d][1]*V2[1][1]+M[d][2]*V2[2][1]+M[d][3]*V2[3][1];
    u2[d]=M[d][0]*V2[0][2]+M[d][1]*V2[1][2]+M[d][2]*V2[2][2]+M[d][3]*V2[3][2];
  }
  {
    float dd = u0[0]*u0[0]+u0[1]*u0[1]+u0[2]*u0[2]+u0[3]*u0[3];
    float in0 = 1.0f/sqrtf(fmaxf(dd,1e-30f));
    #pragma unroll
    for (int d=0;d<4;++d) u0[d]*=in0;
    float p01 = u0[0]*u1[0]+u0[1]*u1[1]+u0[2]*u1[2]+u0[3]*u1[3];
    #pragma unroll
    for (int d=0;d<4;++d) u1[d]-=p01*u0[d];
    dd = u1[0]*u1[0]+u1[1]*u1[1]+u1[2]*u1[2]+u1[3]*u1[3];
    float in1 = 1.0f/sqrtf(fmaxf(dd,1e-30f));
    #pragma unroll
    for (int d=0;d<4;++d) u1[d]*=in1;
    float p02 = u0[0]*u2[0]+u0[1]*u2[1]+u0[2]*u2[2]+u0[3]*u2[3];
    float p12 = u1[0]*u2[0]+u1[1]*u2[1]+u1[2]*u2[2]+u1[3]*u2[3];
    #pragma unroll
    for (int d=0;d<4;++d) u2[d]-=p02*u0[d]+p12*u1[d];
    dd = u2[0]*u2[0]+u2[1]*u2[1]+u2[2]*u2[2]+u2[3]*u2[3];
    float in2 = 1.0f/sqrtf(fmaxf(dd,1e-30f));
    #pragma unroll
    for (int d=0;d<4;++d) u2[d]*=in2;
  }
  #define D3(p,q,r) (u0[p]*(u1[q]*u2[r]-u1[r]*u2[q]) - u1[p]*(u0[q]*u2[r]-u0[r]*u2[q]) + u2[p]*(u0[q]*u1[r]-u0[r]*u1[q]))
  float t3[4];
  t3[0] = -D3(1,2,3); t3[1] = D3(0,2,3); t3[2] = -D3(0,1,3); t3[3] = D3(0,1,2);
  #undef D3
  float dl = (det4(V2) >= 0.0f) ? 1.0f : -1.0f;
  float R[4][4];
  #pragma unroll
  for (int d=0;d<4;++d){
    #pragma unroll
    for (int e=0;e<4;++e)
      R[d][e] = u0[d]*V2[e][0] + u1[d]*V2[e][1] + u2[d]*V2[e][2] + dl*t3[d]*V2[e][3];
  }
  float Wr[4][4];
  Wr[0][0]=Wp[0]; Wr[0][1]=Wr[1][0]=Wp[1]; Wr[0][2]=Wr[2][0]=Wp[2]; Wr[0][3]=Wr[3][0]=Wp[3];
  Wr[1][1]=Wp[4]; Wr[1][2]=Wr[2][1]=Wp[5]; Wr[1][3]=Wr[3][1]=Wp[6];
  Wr[2][2]=Wp[7]; Wr[2][3]=Wr[3][2]=Wp[8]; Wr[3][3]=Wp[9];
  float T[4][4];
  mm44(T, R, Wr);
  #pragma unroll
  for (int d=0;d<4;++d){
    #pragma unroll
    for (int ee=0;ee<4;++ee) Tout[4*d+ee]=T[d][ee];
  }
}

// shared phase-1 body
#define PHASE1(HN, AL, SARR, GARR, IQ) { \
  _Pragma("unroll") \
  for (int j=0;j<4;++j){ \
    float4 h0 = *(const float4*)((HN) + 0*64 + j*16 + (IQ)*4); \
    float4 h1v= *(const float4*)((HN) + 1*64 + j*16 + (IQ)*4); \
    float4 h2 = *(const float4*)((HN) + 2*64 + j*16 + (IQ)*4); \
    float4 h3 = *(const float4*)((HN) + 3*64 + j*16 + (IQ)*4); \
    float4 a0 = *(const float4*)((AL) + 0*64 + j*16 + (IQ)*4); \
    float4 a1 = *(const float4*)((AL) + 1*64 + j*16 + (IQ)*4); \
    float4 a2 = *(const float4*)((AL) + 2*64 + j*16 + (IQ)*4); \
    float4 a3 = *(const float4*)((AL) + 3*64 + j*16 + (IQ)*4); \
    SARR[0]+=dot4f(h0,h0); SARR[1]+=dot4f(h0,h1v); SARR[2]+=dot4f(h0,h2); SARR[3]+=dot4f(h0,h3); \
    SARR[4]+=dot4f(h1v,h1v); SARR[5]+=dot4f(h1v,h2); SARR[6]+=dot4f(h1v,h3); \
    SARR[7]+=dot4f(h2,h2); SARR[8]+=dot4f(h2,h3); SARR[9]+=dot4f(h3,h3); \
    GARR[0]+=dot4f(a0,h0);  GARR[1]+=dot4f(a0,h1v);  GARR[2]+=dot4f(a0,h2);  GARR[3]+=dot4f(a0,h3); \
    GARR[4]+=dot4f(a1,h0);  GARR[5]+=dot4f(a1,h1v);  GARR[6]+=dot4f(a1,h2);  GARR[7]+=dot4f(a1,h3); \
    GARR[8]+=dot4f(a2,h0);  GARR[9]+=dot4f(a2,h1v);  GARR[10]+=dot4f(a2,h2); GARR[11]+=dot4f(a2,h3); \
    GARR[12]+=dot4f(a3,h0); GARR[13]+=dot4f(a3,h1v); GARR[14]+=dot4f(a3,h2); GARR[15]+=dot4f(a3,h3); \
  } }

// fallback-only pass-B macro (LDS atomics, staggered)
#define ZPASS(ACCPTR, HNPTR, TMAT, EV, NQ, IQ) { \
  float* accp = (ACCPTR); \
  _Pragma("unroll") \
  for (int j=0;j<4;++j){ \
    float4 t0 = *(const float4*)((HNPTR) + 0*64 + j*16 + (IQ)*4); \
    float4 t1 = *(const float4*)((HNPTR) + 1*64 + j*16 + (IQ)*4); \
    float4 t2 = *(const float4*)((HNPTR) + 2*64 + j*16 + (IQ)*4); \
    float4 t3 = *(const float4*)((HNPTR) + 3*64 + j*16 + (IQ)*4); \
    float z0[4], z1[4], z2[4], z3[4]; \
    _Pragma("unroll") \
    for (int c=0;c<4;++c){ \
      float x0 = (c==0)?t0.x:(c==1)?t0.y:(c==2)?t0.z:t0.w; \
      float x1 = (c==0)?t1.x:(c==1)?t1.y:(c==2)?t1.z:t1.w; \
      float x2 = (c==0)?t2.x:(c==1)?t2.y:(c==2)?t2.z:t2.w; \
      float x3 = (c==0)?t3.x:(c==1)?t3.y:(c==2)?t3.z:t3.w; \
      z0[c] = TMAT[0][0]*x0+TMAT[0][1]*x1+TMAT[0][2]*x2+TMAT[0][3]*x3; \
      z1[c] = TMAT[1][0]*x0+TMAT[1][1]*x1+TMAT[1][2]*x2+TMAT[1][3]*x3; \
      z2[c] = TMAT[2][0]*x0+TMAT[2][1]*x1+TMAT[2][2]*x2+TMAT[2][3]*x3; \
      z3[c] = TMAT[3][0]*x0+TMAT[3][1]*x1+TMAT[3][2]*x2+TMAT[3][3]*x3; \
    } \
    _Pragma("unroll") \
    for (int dd=0;dd<4;++dd){ \
      int dsel = ((NQ) + dd) & 3; \
      _Pragma("unroll") \
      for (int c=0;c<4;++c){ \
        int csel = (((NQ)>>2) + c) & 3; \
        float zv = \
          (dsel==0)?((csel==0)?z0[0]:(csel==1)?z0[1]:(csel==2)?z0[2]:z0[3]): \
          (dsel==1)?((csel==0)?z1[0]:(csel==1)?z1[1]:(csel==2)?z1[2]:z1[3]): \
          (dsel==2)?((csel==0)?z2[0]:(csel==1)?z2[1]:(csel==2)?z2[2]:z2[3]): \
                    ((csel==0)?z3[0]:(csel==1)?z3[1]:(csel==2)?z3[2]:z3[3]); \
        atomicAdd(accp + dsel*64 + 16*j + 4*(IQ) + csel, (EV)*zv); \
      } \
    } \
  } }

// shared score body: pass A (u) + MLP -> e
#define SCORE_BODY(HN, WMAT, W1L, B1L, W2L, B2V, IQ, EOUT) { \
  float u[16]; \
  _Pragma("unroll") \
  for (int j=0;j<4;++j){ \
    float4 t0 = *(const float4*)((HN) + 0*64 + j*16 + (IQ)*4); \
    float4 t1 = *(const float4*)((HN) + 1*64 + j*16 + (IQ)*4); \
    float4 t2 = *(const float4*)((HN) + 2*64 + j*16 + (IQ)*4); \
    float4 t3 = *(const float4*)((HN) + 3*64 + j*16 + (IQ)*4); \
    _Pragma("unroll") \
    for (int c=0;c<4;++c){ \
      float x0 = (c==0)?t0.x:(c==1)?t0.y:(c==2)?t0.z:t0.w; \
      float x1 = (c==0)?t1.x:(c==1)?t1.y:(c==2)?t1.z:t1.w; \
      float x2 = (c==0)?t2.x:(c==1)?t2.y:(c==2)?t2.z:t2.w; \
      float x3 = (c==0)?t3.x:(c==1)?t3.y:(c==2)?t3.z:t3.w; \
      float w0 = WMAT[0][0]*x0+WMAT[0][1]*x1+WMAT[0][2]*x2+WMAT[0][3]*x3; \
      float w1v= WMAT[1][0]*x0+WMAT[1][1]*x1+WMAT[1][2]*x2+WMAT[1][3]*x3; \
      float w2v= WMAT[2][0]*x0+WMAT[2][1]*x1+WMAT[2][2]*x2+WMAT[2][3]*x3; \
      float w3 = WMAT[3][0]*x0+WMAT[3][1]*x1+WMAT[3][2]*x2+WMAT[3][3]*x3; \
      u[4*j+c] = w0*w0+w1v*w1v+w2v*w2v+w3*w3; \
    } \
  } \
  float h1[16]; \
  _Pragma("unroll") \
  for (int kk=0;kk<16;++kk) h1[kk]=B1L[(IQ)*16+kk]; \
  for (int m=0;m<4;++m){ \
    int qq = (IQ) ^ m; \
    _Pragma("unroll") \
    for (int jl=0;jl<16;++jl){ \
      float uu = __shfl_xor(u[jl], m); \
      int c = 16*(jl>>2) + 4*qq + (jl&3); \
      const float* wr = W1L + c*64 + (IQ)*16; \
      float4 wA=*(const float4*)(wr); \
      float4 wB=*(const float4*)(wr+4); \
      float4 wC=*(const float4*)(wr+8); \
      float4 wD=*(const float4*)(wr+12); \
      h1[0]+=uu*wA.x; h1[1]+=uu*wA.y; h1[2]+=uu*wA.z; h1[3]+=uu*wA.w; \
      h1[4]+=uu*wB.x; h1[5]+=uu*wB.y; h1[6]+=uu*wB.z; h1[7]+=uu*wB.w; \
      h1[8]+=uu*wC.x; h1[9]+=uu*wC.y; h1[10]+=uu*wC.z; h1[11]+=uu*wC.w; \
      h1[12]+=uu*wD.x; h1[13]+=uu*wD.y; h1[14]+=uu*wD.z; h1[15]+=uu*wD.w; \
    } \
  } \
  float sp = 0.0f; \
  _Pragma("unroll") \
  for (int kk=0;kk<16;++kk) sp += gelu_exact(h1[kk]) * W2L[(IQ)*16+kk]; \
  sp += __shfl_xor(sp,1); sp += __shfl_xor(sp,2); \
  EOUT = expf(sp + (B2V)); }

// ================= SPLIT PATH (needs 26*N extra ws floats) =================

// ---- K_sgsvd2: phase 1 + phase 2 in ONE kernel, phase 2 UNIFORM.
// Round-8's fusion failed because phase 2 ran divergent (lane<16 -> 130MB
// spill). Fix: block = 256 nodes. Phase 1 runs 4x 64-node tiles (quad
// layout, arithmetic unchanged), parking S||G (26 floats/node, stride 27 ->
// conflict-free) in LDS. One barrier. Phase 2: ONE NODE PER THREAD, all
// 256 threads uniform — the exact shape round-5's svd_kernel proved
// spill-free. Saves the 13.6MB SG write + read + one launch.
__global__ __launch_bounds__(256, 4) __attribute__((amdgpu_waves_per_eu(4,4)))
void sgsvd2_kernel(const float* __restrict__ H, const float* __restrict__ anchor,
                   float* __restrict__ SGWT, int N)
{
  __shared__ float aL[256];
  __shared__ float sgL[256*SG_STRIDE];   // 27.6 KB
  const int tid = threadIdx.x;
  const int n0 = blockIdx.x * 256;
  const int iq = tid & 3;
  const int nq = tid >> 2;
  aL[tid] = anchor[tid];
  __syncthreads();

  // ---- phase 1: 4 tiles of 64 nodes ----
  for (int t=0;t<4;++t){
    const int node = n0 + t*64 + nq;
    float S[10], G[16];
    #pragma unroll
    for (int r=0;r<10;++r) S[r]=0.0f;
    #pragma unroll
    for (int r=0;r<16;++r) G[r]=0.0f;
    if (node < N){
      const float* Hn = H + (size_t)node*256;
      PHASE1(Hn, aL, S, G, iq)
    }
    #pragma unroll
    for (int r=0;r<10;++r){ S[r]+=__shfl_xor(S[r],1); S[r]+=__shfl_xor(S[r],2); }
    #pragma unroll
    for (int r=0;r<16;++r){ G[r]+=__shfl_xor(G[r],1); G[r]+=__shfl_xor(G[r],2); }
    if (iq==0){
      float* dst = sgL + (t*64 + nq)*SG_STRIDE;
      #pragma unroll
      for (int r=0;r<10;++r) dst[r]=S[r];
      #pragma unroll
      for (int r=0;r<16;++r) dst[10+r]=G[r];
    }
  }
  __syncthreads();

  // ---- phase 2: one node per thread, fully uniform ----
  const int node2 = n0 + tid;
  if (node2 < N){
    const float* src = sgL + tid*SG_STRIDE;
    float Sd[10], Gd[16];
    #pragma unroll
    for (int r=0;r<10;++r) Sd[r]=src[r];
    #pragma unroll
    for (int r=0;r<16;++r) Gd[r]=src[10+r];
    float Wp[10], T[16];
    phase2_body(Sd, Gd, Wp, T);
    #pragma unroll
    for (int r=0;r<10;++r) SGWT[(size_t)r*N + node2] = Wp[r];
    #pragma unroll
    for (int r=0;r<16;++r) SGWT[(size_t)(10+r)*N + node2] = T[r];
  }
}

// ---- K_pool v2 (round-9 exact, measured ~66us): passA+MLP (quad layout)
// -> sync -> passB (channel layout, register accumulation, boundary-flush
// global atomics). ----
__global__ __launch_bounds__(256, 4) __attribute__((amdgpu_waves_per_eu(4,4)))
void pool_kernel(
    const float* __restrict__ H, const int* __restrict__ batch,
    const float* __restrict__ SGWT, const float* __restrict__ w1g,
    const float* __restrict__ b1, const float* __restrict__ w2,
    const float* __restrict__ b2, float* __restrict__ wsAcc, int N)
{
  __shared__ float w1L[4096];                    // 16 KB
  __shared__ __align__(16) float TL[64*20];      // 5.1 KB (T rows, stride 20)
  __shared__ float eL[64];
  __shared__ int   gL[64];
  __shared__ float b1L[64];
  __shared__ float w2L[64];

  const int tid = threadIdx.x;
  const int n0 = blockIdx.x * NPB;
  const int iq = tid & 3;
  const int nq = tid >> 2;

  // ---- staging ----
  for (int i=tid;i<4096;i+=256) w1L[i]=w1g[i];
  for (int i=tid;i<1024;i+=256){            // T: 64 nodes x 16 floats
    int nl = i & 63, r = i >> 6;
    int nd = n0 + nl;
    TL[nl*20 + r] = (nd < N) ? SGWT[(size_t)(10+r)*N + nd] : 0.0f;
  }
  if (tid < 64){
    int nd = n0 + tid;
    gL[tid] = batch[nd < N ? nd : (N-1)];
    eL[tid] = 0.0f;
    b1L[tid]=b1[tid]; w2L[tid]=w2[tid];
  }
  __syncthreads();

  const int node = n0 + nq;
  const bool valid = node < N;
  const float b2v = b2[0];

  // ---- pass A + MLP (quad layout) ----
  if (valid){
    const float* Hn = H + (size_t)node*256;
    float Wq[10];
    #pragma unroll
    for (int r=0;r<10;++r) Wq[r]=SGWT[(size_t)r*N + node];
    float Wm[4][4];
    Wm[0][0]=Wq[0]; Wm[0][1]=Wm[1][0]=Wq[1]; Wm[0][2]=Wm[2][0]=Wq[2]; Wm[0][3]=Wm[3][0]=Wq[3];
    Wm[1][1]=Wq[4]; Wm[1][2]=Wm[2][1]=Wq[5]; Wm[1][3]=Wm[3][1]=Wq[6];
    Wm[2][2]=Wq[7]; Wm[2][3]=Wm[3][2]=Wq[8]; Wm[3][3]=Wq[9];
    float e;
    SCORE_BODY(Hn, Wm, w1L, b1L, w2L, b2v, iq, e)
    if (iq==0) eL[nq] = e;
  }
  __syncthreads();

  // ---- pass B (channel layout, register accumulation) ----
  {
    const int c    = tid & 63;          // channel
    const int base = (tid >> 6) * 16;   // this wave's 16-node run
    float a0=0.0f,a1=0.0f,a2=0.0f,a3=0.0f,aE=0.0f;
    int gcur = gL[base];
    for (int i=0;i<16;++i){
      int nl = base + i;
      int nd = n0 + nl;
      if (nd >= N) break;               // wave-uniform
      int g = gL[nl];
      if (g != gcur){                   // wave-uniform boundary flush
        float* wp = wsAcc + (size_t)gcur*WSG_STRIDE;
        atomicAdd(wp +        c, a0);
        atomicAdd(wp +  64 +  c, a1);
        atomicAdd(wp + 128 +  c, a2);
        atomicAdd(wp + 192 +  c, a3);
        if (c==0) atomicAdd(wp + 256, aE);
        a0=a1=a2=a3=aE=0.0f; gcur=g;
      }
      float e = eL[nl];                 // broadcast
      const float* Hn2 = H + (size_t)nd*256;
      float h0 = Hn2[       c];
      float h1 = Hn2[ 64 +  c];
      float h2 = Hn2[128 +  c];
      float h3 = Hn2[192 +  c];
      const float* t = TL + nl*20;
      float4 T0 = *(const float4*)(t);      // broadcast b128
      float4 T1 = *(const float4*)(t+4);
      float4 T2 = *(const float4*)(t+8);
      float4 T3 = *(const float4*)(t+12);
      a0 += e*(T0.x*h0 + T0.y*h1 + T0.z*h2 + T0.w*h3);
      a1 += e*(T1.x*h0 + T1.y*h1 + T1.z*h2 + T1.w*h3);
      a2 += e*(T2.x*h0 + T2.y*h1 + T2.z*h2 + T2.w*h3);
      a3 += e*(T3.x*h0 + T3.y*h1 + T3.z*h2 + T3.w*h3);
      aE += e;
    }
    float* wp = wsAcc + (size_t)gcur*WSG_STRIDE;
    atomicAdd(wp +        c, a0);
    atomicAdd(wp +  64 +  c, a1);
    atomicAdd(wp + 128 +  c, a2);
    atomicAdd(wp + 192 +  c, a3);
    if (c==0) atomicAdd(wp + 256, aE);
  }
}

// ============ FUSED FALLBACK (round-2-style, 1.06 MB ws) ============
__global__ __launch_bounds__(256, 3) __attribute__((amdgpu_waves_per_eu(3,3)))
void node_kernel(
    const float* __restrict__ H, const int* __restrict__ batch,
    const float* __restrict__ anchor, const float* __restrict__ w1g,
    const float* __restrict__ b1, const float* __restrict__ w2,
    const float* __restrict__ b2, float* __restrict__ wsAcc, int N)
{
  __shared__ float w1L[4096];
  __shared__ float accL[MAXG*ACC_STRIDE];
  __shared__ float aL[256];
  __shared__ float b1L[64];
  __shared__ float w2L[64];

  const int tid = threadIdx.x;
  const int n0 = blockIdx.x * NPB;
  const int iq = tid & 3;
  const int nq = tid >> 2;
  const int lane = tid & 63;

  for (int i=tid;i<4096;i+=256) w1L[i]=w1g[i];
  aL[tid]=anchor[tid];
  if (tid < 64){ b1L[tid]=b1[tid]; w2L[tid]=w2[tid]; }
  for (int i=tid;i<MAXG*ACC_STRIDE;i+=256) accL[i]=0.0f;
  __syncthreads();

  const int node = n0 + nq;
  const bool valid = node < N;

  float S[10], G[16];
  #pragma unroll
  for (int r=0;r<10;++r) S[r]=0.0f;
  #pragma unroll
  for (int r=0;r<16;++r) G[r]=0.0f;
  if (valid){
    const float* Hn = H + (size_t)node*256;
    PHASE1(Hn, aL, S, G, iq)
  }
  #pragma unroll
  for (int r=0;r<10;++r){ S[r]+=__shfl_xor(S[r],1); S[r]+=__shfl_xor(S[r],2); }
  #pragma unroll
  for (int r=0;r<16;++r){ G[r]+=__shfl_xor(G[r],1); G[r]+=__shfl_xor(G[r],2); }

  const int srcOwn = (lane & 15) << 2;
  float Sd[10], Gd[16];
  #pragma unroll
  for (int r=0;r<10;++r) Sd[r]=__shfl(S[r], srcOwn);
  #pragma unroll
  for (int r=0;r<16;++r) Gd[r]=__shfl(G[r], srcOwn);

  float Wp[10], Tm[16];
  #pragma unroll
  for (int r=0;r<10;++r) Wp[r]=0.0f;
  #pragma unroll
  for (int r=0;r<16;++r) Tm[r]=0.0f;
  {
    const int node2 = n0 + ((tid>>6)<<4) + (lane & 15);
    if (lane < 16 && node2 < N){
      phase2_body(Sd, Gd, Wp, Tm);
    }
  }

  const float b2v = b2[0];
  const int gFirst = batch[n0];
  const int srcNode = lane >> 2;

  float Wq[10], Tq[16];
  #pragma unroll
  for (int r=0;r<10;++r) Wq[r]=__shfl(Wp[r], srcNode);
  #pragma unroll
  for (int r=0;r<16;++r) Tq[r]=__shfl(Tm[r], srcNode);

  if (valid){
    const float* Hn = H + (size_t)node*256;
    float Wm[4][4];
    Wm[0][0]=Wq[0]; Wm[0][1]=Wm[1][0]=Wq[1]; Wm[0][2]=Wm[2][0]=Wq[2]; Wm[0][3]=Wm[3][0]=Wq[3];
    Wm[1][1]=Wq[4]; Wm[1][2]=Wm[2][1]=Wq[5]; Wm[1][3]=Wm[3][1]=Wq[6];
    Wm[2][2]=Wq[7]; Wm[2][3]=Wm[3][2]=Wq[8]; Wm[3][3]=Wq[9];
    float e;
    SCORE_BODY(Hn, Wm, w1L, b1L, w2L, b2v, iq, e)

    asm volatile("" ::: "memory");
    float T[4][4];
    #pragma unroll
    for (int d=0;d<4;++d){
      #pragma unroll
      for (int e2=0;e2<4;++e2) T[d][e2]=Tq[4*d+e2];
    }
    int g  = batch[node];
    int gl = g - gFirst;
    if (gl < MAXG){
      ZPASS(accL + gl*ACC_STRIDE, Hn, T, e, nq, iq)
      if (iq==0) atomicAdd(accL + gl*ACC_STRIDE + 256, e);
    } else {
      ZPASS(wsAcc + (size_t)g*WSG_STRIDE, Hn, T, e, nq, iq)
      if (iq==0) atomicAdd(wsAcc + (size_t)g*WSG_STRIDE + 256, e);
    }
  }
  __syncthreads();

  {
    int lastIdx = n0+NPB-1 < N ? n0+NPB-1 : N-1;
    int gLast = batch[lastIdx];
    int ngl = gLast - gFirst + 1; if (ngl > MAXG) ngl = MAXG;
    for (int idx=tid; idx<ngl*ACC_STRIDE; idx+=256){
      int gl = idx / ACC_STRIDE;
      int sl = idx - gl*ACC_STRIDE;
      float v = accL[idx];
      if (v != 0.0f) atomicAdd(wsAcc + (size_t)(gFirst+gl)*WSG_STRIDE + sl, v);
    }
  }
}

// ---------------- per-graph MLP + LayerNorm + reduce ----------------
__global__ __launch_bounds__(256) void finalize_kernel(
    const float* __restrict__ wsAcc, const float* __restrict__ token,
    const float* __restrict__ wc1, const float* __restrict__ bc1,
    const float* __restrict__ wc2, const float* __restrict__ bc2,
    const float* __restrict__ lng, const float* __restrict__ lnb,
    float* __restrict__ out)
{
  __shared__ float comb[4][128];
  __shared__ float hcL[4][64];
  __shared__ float upsq[4][64];
  const int g = blockIdx.x, tid = threadIdx.x;
  const int d = tid >> 6, k = tid & 63;
  const float* wsg = wsAcc + (size_t)g*WSG_STRIDE;
  float denom = wsg[256];
  float inv = (denom != 0.0f) ? 1.0f/denom : 0.0f;
  for (int i=tid;i<512;i+=256){
    int dd=i>>7, j=i&127;
    comb[dd][j] = (j<64) ? token[dd*64+j] : wsg[dd*64+(j-64)]*inv;
  }
  __syncthreads();
  float acc = bc1[k];
  for (int j=0;j<128;++j) acc += comb[d][j]*wc1[j*64+k];
  hcL[d][k] = gelu_exact(acc);
  __syncthreads();
  float acc2 = bc2[k];
  for (int j=0;j<64;++j) acc2 += hcL[d][j]*wc2[j*64+k];
  float s1 = acc2, s2 = acc2*acc2;
  #pragma unroll
  for (int m=1;m<64;m<<=1){ s1 += __shfl_xor(s1,m); s2 += __shfl_xor(s2,m); }
  float mu  = s1*(1.0f/64.0f);
  float var = s2*(1.0f/64.0f) - mu*mu;
  float up = (acc2 - mu)*(1.0f/sqrtf(var + 1e-5f))*lng[k] + lnb[k];
  upsq[d][k] = up*up;
  __syncthreads();
  if (tid < 64)
    out[(size_t)g*64 + tid] = upsq[0][tid]+upsq[1][tid]+upsq[2][tid]+upsq[3][tid];
}

extern "C" void kernel_launch(void* const* d_in, const int* in_sizes, int n_in,
                              void* d_out, int out_size, void* d_ws, size_t ws_size,
                              hipStream_t stream) {
  (void)n_in;
  const float* H      = (const float*)d_in[0];
  const int*   batch  = (const int*)  d_in[1];
  const float* anchor = (const float*)d_in[3];
  const float* w1     = (const float*)d_in[4];
  const float* b1     = (const float*)d_in[5];
  const float* w2     = (const float*)d_in[6];
  const float* b2     = (const float*)d_in[7];
  const float* token  = (const float*)d_in[8];
  const float* wc1    = (const float*)d_in[9];
  const float* bc1    = (const float*)d_in[10];
  const float* wc2    = (const float*)d_in[11];
  const float* bc2    = (const float*)d_in[12];
  const float* ln_g   = (const float*)d_in[13];
  const float* ln_b   = (const float*)d_in[14];
  float* out = (float*)d_out;

  const int N = in_sizes[0] / 256;   // nodes
  const int B = out_size / 64;       // graphs
  const int nb = (N + NPB - 1)/NPB;

  float* wsAcc = (float*)d_ws;       // B*WSG_STRIDE floats
  const size_t needBase  = (size_t)B*WSG_STRIDE*sizeof(float);
  const size_t needSplit = needBase + (size_t)26*N*sizeof(float);

  hipMemsetAsync(wsAcc, 0, needBase, stream);

  if (ws_size >= needSplit){
    // split path: sgsvd2(uniform fused) -> pool(passA+MLP+regacc-passB)
    float* SGWT = wsAcc + (size_t)B*WSG_STRIDE;   // 26*N floats: W||T
    const int nb2 = (N + 255)/256;
    sgsvd2_kernel<<<nb2, 256, 0, stream>>>(H, anchor, SGWT, N);
    pool_kernel<<<nb, 256, 0, stream>>>(H, batch, SGWT, w1, b1, w2, b2, wsAcc, N);
  } else {
    // fused fallback: fits in B*WSG_STRIDE floats
    node_kernel<<<nb, 256, 0, stream>>>(H, batch, anchor, w1, b1, w2, b2, wsAcc, N);
  }
  finalize_kernel<<<B, 256, 0, stream>>>(wsAcc, token, wc1, bc1, wc2, bc2, ln_g, ln_b, out);
}

// Round 11
// 314.349 us; speedup vs baseline: 1.0445x; 1.0445x over previous
//
#include <hip/hip_runtime.h>
#include <math.h>

#define WSG_STRIDE 260    // per-graph accum: 256 num + 1 denom (+pad)
#define ACC_STRIDE 257    // per-graph slots in LDS accumulator (fallback only)
#define MAXG 4            // fallback kernel only
#define NPB 64            // nodes per block (pool/fallback)

__device__ __forceinline__ float dot4f(float4 a, float4 b){
  return a.x*b.x + a.y*b.y + a.z*b.z + a.w*b.w;
}
__device__ __forceinline__ float gelu_exact(float x){
  return 0.5f*x*(1.0f+erff(x*0.70710678118654752440f));
}
__device__ __forceinline__ void mm44(float o[4][4], const float a[4][4], const float b[4][4]){
  #pragma unroll
  for (int i=0;i<4;++i){
    #pragma unroll
    for (int j=0;j<4;++j)
      o[i][j] = a[i][0]*b[0][j] + a[i][1]*b[1][j] + a[i][2]*b[2][j] + a[i][3]*b[3][j];
  }
}

template<int P,int Q,int K1,int K2>
__device__ __forceinline__ void jrot(float a[4][4], float V[4][4]){
  float apq = a[P][Q];
  if (fabsf(apq) > 1e-30f){
    float app=a[P][P], aqq=a[Q][Q];
    float tau=(aqq-app)/(2.0f*apq);
    float t=copysignf(1.0f,tau)/(fabsf(tau)+sqrtf(1.0f+tau*tau));
    float c=1.0f/sqrtf(1.0f+t*t), s=t*c;
    float a1p=a[K1][P], a1q=a[K1][Q];
    a[K1][P]=c*a1p-s*a1q; a[P][K1]=a[K1][P];
    a[K1][Q]=s*a1p+c*a1q; a[Q][K1]=a[K1][Q];
    float a2p=a[K2][P], a2q=a[K2][Q];
    a[K2][P]=c*a2p-s*a2q; a[P][K2]=a[K2][P];
    a[K2][Q]=s*a2p+c*a2q; a[Q][K2]=a[K2][Q];
    a[P][P]=app-t*apq; a[Q][Q]=aqq+t*apq; a[P][Q]=0.0f; a[Q][P]=0.0f;
    #pragma unroll
    for (int r=0;r<4;++r){ float vp=V[r][P], vq=V[r][Q]; V[r][P]=c*vp-s*vq; V[r][Q]=s*vp+c*vq; }
  }
}

__device__ __forceinline__ void jacobi4(float a[4][4], float V[4][4], int sweeps){
  #pragma unroll
  for (int i=0;i<4;++i){
    #pragma unroll
    for (int j=0;j<4;++j) V[i][j] = (i==j)?1.0f:0.0f;
  }
  for (int sw=0; sw<sweeps; ++sw){
    jrot<0,1,2,3>(a,V); jrot<0,2,1,3>(a,V); jrot<0,3,1,2>(a,V);
    jrot<1,2,0,3>(a,V); jrot<1,3,0,2>(a,V); jrot<2,3,0,1>(a,V);
  }
}

__device__ __forceinline__ float det4(const float V[4][4]){
  float s0 = V[0][0]*V[1][1] - V[0][1]*V[1][0];
  float s1 = V[0][0]*V[1][2] - V[0][2]*V[1][0];
  float s2 = V[0][0]*V[1][3] - V[0][3]*V[1][0];
  float s3 = V[0][1]*V[1][2] - V[0][2]*V[1][1];
  float s4 = V[0][1]*V[1][3] - V[0][3]*V[1][1];
  float s5 = V[0][2]*V[1][3] - V[0][3]*V[1][2];
  float c5 = V[2][2]*V[3][3] - V[2][3]*V[3][2];
  float c4 = V[2][1]*V[3][3] - V[2][3]*V[3][1];
  float c3 = V[2][1]*V[3][2] - V[2][2]*V[3][1];
  float c2 = V[2][0]*V[3][3] - V[2][3]*V[3][0];
  float c1 = V[2][0]*V[3][2] - V[2][2]*V[3][0];
  float c0 = V[2][0]*V[3][1] - V[2][1]*V[3][0];
  return s0*c5 - s1*c4 + s2*c3 + s3*c2 - s4*c1 + s5*c0;
}

// ============ device-side phase-2 body (shared) ============
// ALLOCATOR RULE (measured, rounds 1/2/4/6/7/8/10): this body may ONLY live
// in a kernel where it is the sole content, one node per thread, uniform
// control flow, (256,3)+wpe(3,3). Any co-residence with streaming phases
// or divergent guards -> hipcc compresses VGPRs below budget and spills
// the whole live set to scratch (65-130MB WRITE_SIZE signature).
__device__ __forceinline__ void phase2_body(const float Sd[10], const float Gd[16],
                                            float Wp[10], float Tout[16]){
  float a00=Sd[0]+1e-4f, a01=Sd[1], a02=Sd[2], a03=Sd[3];
  float a11=Sd[4]+1e-4f, a12=Sd[5], a13=Sd[6];
  float a22=Sd[7]+1e-4f, a23=Sd[8], a33=Sd[9]+1e-4f;
  float Gm[4][4];
  #pragma unroll
  for (int d=0;d<4;++d){
    #pragma unroll
    for (int f=0;f<4;++f) Gm[d][f]=Gd[4*d+f];
  }
  float cs = 0.4f*(a00+a11+a22+a33);
  float rc = 1.0f/cs;
  float Y[4][4], Z[4][4];
  Y[0][0]=a00*rc; Y[0][1]=Y[1][0]=a01*rc; Y[0][2]=Y[2][0]=a02*rc; Y[0][3]=Y[3][0]=a03*rc;
  Y[1][1]=a11*rc; Y[1][2]=Y[2][1]=a12*rc; Y[1][3]=Y[3][1]=a13*rc;
  Y[2][2]=a22*rc; Y[2][3]=Y[3][2]=a23*rc; Y[3][3]=a33*rc;
  #pragma unroll
  for (int i=0;i<4;++i){
    #pragma unroll
    for (int j=0;j<4;++j) Z[i][j]=(i==j)?1.0f:0.0f;
  }
  #pragma unroll
  for (int it=0; it<8; ++it){
    float P[4][4], Y2[4][4], Z2[4][4];
    mm44(P, Z, Y);
    #pragma unroll
    for (int i=0;i<4;++i){
      #pragma unroll
      for (int j=0;j<4;++j) P[i][j] = (i==j) ? 1.5f-0.5f*P[i][j] : -0.5f*P[i][j];
    }
    mm44(Y2, Y, P);
    mm44(Z2, P, Z);
    #pragma unroll
    for (int i=0;i<4;++i){
      #pragma unroll
      for (int j=0;j<4;++j){ Y[i][j]=Y2[i][j]; Z[i][j]=Z2[i][j]; }
    }
  }
  float rsc = rsqrtf(cs);
  float Wm[4][4];
  #pragma unroll
  for (int i=0;i<4;++i){
    #pragma unroll
    for (int j=0;j<4;++j) Wm[i][j] = Z[i][j]*rsc;
  }
  Wp[0]=Wm[0][0]; Wp[1]=Wm[0][1]; Wp[2]=Wm[0][2]; Wp[3]=Wm[0][3];
  Wp[4]=Wm[1][1]; Wp[5]=Wm[1][2]; Wp[6]=Wm[1][3];
  Wp[7]=Wm[2][2]; Wp[8]=Wm[2][3]; Wp[9]=Wm[3][3];
  float M[4][4];
  mm44(M, Gm, Wm);
  float A2[4][4];
  #pragma unroll
  for (int i=0;i<4;++i){
    #pragma unroll
    for (int j=0;j<4;++j)
      A2[i][j] = M[0][i]*M[0][j] + M[1][i]*M[1][j] + M[2][i]*M[2][j] + M[3][i]*M[3][j];
  }
  float V2[4][4];
  jacobi4(A2, V2, 4);
  float mu[4];
  #pragma unroll
  for (int i=0;i<4;++i) mu[i]=A2[i][i];
  #define CSW(I,J) if (mu[I] < mu[J]) { float tw; \
    tw=mu[I]; mu[I]=mu[J]; mu[J]=tw; \
    tw=V2[0][I]; V2[0][I]=V2[0][J]; V2[0][J]=tw; \
    tw=V2[1][I]; V2[1][I]=V2[1][J]; V2[1][J]=tw; \
    tw=V2[2][I]; V2[2][I]=V2[2][J]; V2[2][J]=tw; \
    tw=V2[3][I]; V2[3][I]=V2[3][J]; V2[3][J]=tw; }
  CSW(0,1) CSW(2,3) CSW(0,2) CSW(1,3) CSW(1,2)
  #undef CSW
  float u0[4],u1[4],u2[4];
  #pragma unroll
  for (int d=0;d<4;++d){
    u0[d]=M[d][0]*V2[0][0]+M[d][1]*V2[1][0]+M[d][2]*V2[2][0]+M[d][3]*V2[3][0];
    u1[d]=M[d][0]*V2[0][1]+M[d][1]*V2[1][1]+M[d][2]*V2[2][1]+M[d][3]*V2[3][1];
    u2[d]=M[d][0]*V2[0][2]+M[d][1]*V2[1][2]+M[d][2]*V2[2][2]+M[d][3]*V2[3][2];
  }
  {
    float dd = u0[0]*u0[0]+u0[1]*u0[1]+u0[2]*u0[2]+u0[3]*u0[3];
    float in0 = 1.0f/sqrtf(fmaxf(dd,1e-30f));
    #pragma unroll
    for (int d=0;d<4;++d) u0[d]*=in0;
    float p01 = u0[0]*u1[0]+u0[1]*u1[1]+u0[2]*u1[2]+u0[3]*u1[3];
    #pragma unroll
    for (int d=0;d<4;++d) u1[d]-=p01*u0[d];
    dd = u1[0]*u1[0]+u1[1]*u1[1]+u1[2]*u1[2]+u1[3]*u1[3];
    float in1 = 1.0f/sqrtf(fmaxf(dd,1e-30f));
    #pragma unroll
    for (int d=0;d<4;++d) u1[d]*=in1;
    float p02 = u0[0]*u2[0]+u0[1]*u2[1]+u0[2]*u2[2]+u0[3]*u2[3];
    float p12 = u1[0]*u2[0]+u1[1]*u2[1]+u1[2]*u2[2]+u1[3]*u2[3];
    #pragma unroll
    for (int d=0;d<4;++d) u2[d]-=p02*u0[d]+p12*u1[d];
    dd = u2[0]*u2[0]+u2[1]*u2[1]+u2[2]*u2[2]+u2[3]*u2[3];
    float in2 = 1.0f/sqrtf(fmaxf(dd,1e-30f));
    #pragma unroll
    for (int d=0;d<4;++d) u2[d]*=in2;
  }
  #define D3(p,q,r) (u0[p]*(u1[q]*u2[r]-u1[r]*u2[q]) - u1[p]*(u0[q]*u2[r]-u0[r]*u2[q]) + u2[p]*(u0[q]*u1[r]-u0[r]*u1[q]))
  float t3[4];
  t3[0] = -D3(1,2,3); t3[1] = D3(0,2,3); t3[2] = -D3(0,1,3); t3[3] = D3(0,1,2);
  #undef D3
  float dl = (det4(V2) >= 0.0f) ? 1.0f : -1.0f;
  float R[4][4];
  #pragma unroll
  for (int d=0;d<4;++d){
    #pragma unroll
    for (int e=0;e<4;++e)
      R[d][e] = u0[d]*V2[e][0] + u1[d]*V2[e][1] + u2[d]*V2[e][2] + dl*t3[d]*V2[e][3];
  }
  float Wr[4][4];
  Wr[0][0]=Wp[0]; Wr[0][1]=Wr[1][0]=Wp[1]; Wr[0][2]=Wr[2][0]=Wp[2]; Wr[0][3]=Wr[3][0]=Wp[3];
  Wr[1][1]=Wp[4]; Wr[1][2]=Wr[2][1]=Wp[5]; Wr[1][3]=Wr[3][1]=Wp[6];
  Wr[2][2]=Wp[7]; Wr[2][3]=Wr[3][2]=Wp[8]; Wr[3][3]=Wp[9];
  float T[4][4];
  mm44(T, R, Wr);
  #pragma unroll
  for (int d=0;d<4;++d){
    #pragma unroll
    for (int ee=0;ee<4;++ee) Tout[4*d+ee]=T[d][ee];
  }
}

// shared phase-1 body
#define PHASE1(HN, AL, SARR, GARR, IQ) { \
  _Pragma("unroll") \
  for (int j=0;j<4;++j){ \
    float4 h0 = *(const float4*)((HN) + 0*64 + j*16 + (IQ)*4); \
    float4 h1v= *(const float4*)((HN) + 1*64 + j*16 + (IQ)*4); \
    float4 h2 = *(const float4*)((HN) + 2*64 + j*16 + (IQ)*4); \
    float4 h3 = *(const float4*)((HN) + 3*64 + j*16 + (IQ)*4); \
    float4 a0 = *(const float4*)((AL) + 0*64 + j*16 + (IQ)*4); \
    float4 a1 = *(const float4*)((AL) + 1*64 + j*16 + (IQ)*4); \
    float4 a2 = *(const float4*)((AL) + 2*64 + j*16 + (IQ)*4); \
    float4 a3 = *(const float4*)((AL) + 3*64 + j*16 + (IQ)*4); \
    SARR[0]+=dot4f(h0,h0); SARR[1]+=dot4f(h0,h1v); SARR[2]+=dot4f(h0,h2); SARR[3]+=dot4f(h0,h3); \
    SARR[4]+=dot4f(h1v,h1v); SARR[5]+=dot4f(h1v,h2); SARR[6]+=dot4f(h1v,h3); \
    SARR[7]+=dot4f(h2,h2); SARR[8]+=dot4f(h2,h3); SARR[9]+=dot4f(h3,h3); \
    GARR[0]+=dot4f(a0,h0);  GARR[1]+=dot4f(a0,h1v);  GARR[2]+=dot4f(a0,h2);  GARR[3]+=dot4f(a0,h3); \
    GARR[4]+=dot4f(a1,h0);  GARR[5]+=dot4f(a1,h1v);  GARR[6]+=dot4f(a1,h2);  GARR[7]+=dot4f(a1,h3); \
    GARR[8]+=dot4f(a2,h0);  GARR[9]+=dot4f(a2,h1v);  GARR[10]+=dot4f(a2,h2); GARR[11]+=dot4f(a2,h3); \
    GARR[12]+=dot4f(a3,h0); GARR[13]+=dot4f(a3,h1v); GARR[14]+=dot4f(a3,h2); GARR[15]+=dot4f(a3,h3); \
  } }

// fallback-only pass-B macro (LDS atomics, staggered)
#define ZPASS(ACCPTR, HNPTR, TMAT, EV, NQ, IQ) { \
  float* accp = (ACCPTR); \
  _Pragma("unroll") \
  for (int j=0;j<4;++j){ \
    float4 t0 = *(const float4*)((HNPTR) + 0*64 + j*16 + (IQ)*4); \
    float4 t1 = *(const float4*)((HNPTR) + 1*64 + j*16 + (IQ)*4); \
    float4 t2 = *(const float4*)((HNPTR) + 2*64 + j*16 + (IQ)*4); \
    float4 t3 = *(const float4*)((HNPTR) + 3*64 + j*16 + (IQ)*4); \
    float z0[4], z1[4], z2[4], z3[4]; \
    _Pragma("unroll") \
    for (int c=0;c<4;++c){ \
      float x0 = (c==0)?t0.x:(c==1)?t0.y:(c==2)?t0.z:t0.w; \
      float x1 = (c==0)?t1.x:(c==1)?t1.y:(c==2)?t1.z:t1.w; \
      float x2 = (c==0)?t2.x:(c==1)?t2.y:(c==2)?t2.z:t2.w; \
      float x3 = (c==0)?t3.x:(c==1)?t3.y:(c==2)?t3.z:t3.w; \
      z0[c] = TMAT[0][0]*x0+TMAT[0][1]*x1+TMAT[0][2]*x2+TMAT[0][3]*x3; \
      z1[c] = TMAT[1][0]*x0+TMAT[1][1]*x1+TMAT[1][2]*x2+TMAT[1][3]*x3; \
      z2[c] = TMAT[2][0]*x0+TMAT[2][1]*x1+TMAT[2][2]*x2+TMAT[2][3]*x3; \
      z3[c] = TMAT[3][0]*x0+TMAT[3][1]*x1+TMAT[3][2]*x2+TMAT[3][3]*x3; \
    } \
    _Pragma("unroll") \
    for (int dd=0;dd<4;++dd){ \
      int dsel = ((NQ) + dd) & 3; \
      _Pragma("unroll") \
      for (int c=0;c<4;++c){ \
        int csel = (((NQ)>>2) + c) & 3; \
        float zv = \
          (dsel==0)?((csel==0)?z0[0]:(csel==1)?z0[1]:(csel==2)?z0[2]:z0[3]): \
          (dsel==1)?((csel==0)?z1[0]:(csel==1)?z1[1]:(csel==2)?z1[2]:z1[3]): \
          (dsel==2)?((csel==0)?z2[0]:(csel==1)?z2[1]:(csel==2)?z2[2]:z2[3]): \
                    ((csel==0)?z3[0]:(csel==1)?z3[1]:(csel==2)?z3[2]:z3[3]); \
        atomicAdd(accp + dsel*64 + 16*j + 4*(IQ) + csel, (EV)*zv); \
      } \
    } \
  } }

// shared score body: pass A (u) + MLP -> e
#define SCORE_BODY(HN, WMAT, W1L, B1L, W2L, B2V, IQ, EOUT) { \
  float u[16]; \
  _Pragma("unroll") \
  for (int j=0;j<4;++j){ \
    float4 t0 = *(const float4*)((HN) + 0*64 + j*16 + (IQ)*4); \
    float4 t1 = *(const float4*)((HN) + 1*64 + j*16 + (IQ)*4); \
    float4 t2 = *(const float4*)((HN) + 2*64 + j*16 + (IQ)*4); \
    float4 t3 = *(const float4*)((HN) + 3*64 + j*16 + (IQ)*4); \
    _Pragma("unroll") \
    for (int c=0;c<4;++c){ \
      float x0 = (c==0)?t0.x:(c==1)?t0.y:(c==2)?t0.z:t0.w; \
      float x1 = (c==0)?t1.x:(c==1)?t1.y:(c==2)?t1.z:t1.w; \
      float x2 = (c==0)?t2.x:(c==1)?t2.y:(c==2)?t2.z:t2.w; \
      float x3 = (c==0)?t3.x:(c==1)?t3.y:(c==2)?t3.z:t3.w; \
      float w0 = WMAT[0][0]*x0+WMAT[0][1]*x1+WMAT[0][2]*x2+WMAT[0][3]*x3; \
      float w1v= WMAT[1][0]*x0+WMAT[1][1]*x1+WMAT[1][2]*x2+WMAT[1][3]*x3; \
      float w2v= WMAT[2][0]*x0+WMAT[2][1]*x1+WMAT[2][2]*x2+WMAT[2][3]*x3; \
      float w3 = WMAT[3][0]*x0+WMAT[3][1]*x1+WMAT[3][2]*x2+WMAT[3][3]*x3; \
      u[4*j+c] = w0*w0+w1v*w1v+w2v*w2v+w3*w3; \
    } \
  } \
  float h1[16]; \
  _Pragma("unroll") \
  for (int kk=0;kk<16;++kk) h1[kk]=B1L[(IQ)*16+kk]; \
  for (int m=0;m<4;++m){ \
    int qq = (IQ) ^ m; \
    _Pragma("unroll") \
    for (int jl=0;jl<16;++jl){ \
      float uu = __shfl_xor(u[jl], m); \
      int c = 16*(jl>>2) + 4*qq + (jl&3); \
      const float* wr = W1L + c*64 + (IQ)*16; \
      float4 wA=*(const float4*)(wr); \
      float4 wB=*(const float4*)(wr+4); \
      float4 wC=*(const float4*)(wr+8); \
      float4 wD=*(const float4*)(wr+12); \
      h1[0]+=uu*wA.x; h1[1]+=uu*wA.y; h1[2]+=uu*wA.z; h1[3]+=uu*wA.w; \
      h1[4]+=uu*wB.x; h1[5]+=uu*wB.y; h1[6]+=uu*wB.z; h1[7]+=uu*wB.w; \
      h1[8]+=uu*wC.x; h1[9]+=uu*wC.y; h1[10]+=uu*wC.z; h1[11]+=uu*wC.w; \
      h1[12]+=uu*wD.x; h1[13]+=uu*wD.y; h1[14]+=uu*wD.z; h1[15]+=uu*wD.w; \
    } \
  } \
  float sp = 0.0f; \
  _Pragma("unroll") \
  for (int kk=0;kk<16;++kk) sp += gelu_exact(h1[kk]) * W2L[(IQ)*16+kk]; \
  sp += __shfl_xor(sp,1); sp += __shfl_xor(sp,2); \
  EOUT = expf(sp + (B2V)); }

// ================= SPLIT PATH (needs 26*N extra ws floats) =================

// ---- K_sg: phase 1 (round-9 exact) ----
__global__ __launch_bounds__(256, 4) __attribute__((amdgpu_waves_per_eu(4,4)))
void sg_kernel(const float* __restrict__ H, const float* __restrict__ anchor,
               float* __restrict__ SGWT, int N)
{
  __shared__ float aL[256];
  const int tid = threadIdx.x;
  const int n0 = blockIdx.x * NPB;
  const int iq = tid & 3;
  const int nq = tid >> 2;
  aL[tid] = anchor[tid];
  __syncthreads();
  const int node = n0 + nq;
  if (node >= N) return;

  const float* Hn = H + (size_t)node*256;
  float S[10], G[16];
  #pragma unroll
  for (int r=0;r<10;++r) S[r]=0.0f;
  #pragma unroll
  for (int r=0;r<16;++r) G[r]=0.0f;
  PHASE1(Hn, aL, S, G, iq)
  #pragma unroll
  for (int r=0;r<10;++r){ S[r]+=__shfl_xor(S[r],1); S[r]+=__shfl_xor(S[r],2); }
  #pragma unroll
  for (int r=0;r<16;++r){ G[r]+=__shfl_xor(G[r],1); G[r]+=__shfl_xor(G[r],2); }
  if (iq==0){
    #pragma unroll
    for (int r=0;r<10;++r) SGWT[(size_t)r*N + node] = S[r];
    #pragma unroll
    for (int r=0;r<16;++r) SGWT[(size_t)(10+r)*N + node] = G[r];
  }
}

// ---- K_svd: phase 2 — SOLE content, one node/thread, uniform (round-9 exact)
__global__ __launch_bounds__(256, 3) __attribute__((amdgpu_waves_per_eu(3,3)))
void svd_kernel(float* __restrict__ SGWT, int N)
{
  const int node = blockIdx.x*256 + threadIdx.x;
  if (node >= N) return;
  float Sd[10], Gd[16];
  #pragma unroll
  for (int r=0;r<10;++r) Sd[r]=SGWT[(size_t)r*N + node];
  #pragma unroll
  for (int r=0;r<16;++r) Gd[r]=SGWT[(size_t)(10+r)*N + node];
  float Wp[10], T[16];
  phase2_body(Sd, Gd, Wp, T);
  #pragma unroll
  for (int r=0;r<10;++r) SGWT[(size_t)r*N + node] = Wp[r];
  #pragma unroll
  for (int r=0;r<16;++r) SGWT[(size_t)(10+r)*N + node] = T[r];
}

// ---- K_pool v2 (round-9 exact, measured ~66us): passA+MLP (quad layout)
// -> sync -> passB (channel layout, register accumulation, boundary-flush
// global atomics). ----
__global__ __launch_bounds__(256, 4) __attribute__((amdgpu_waves_per_eu(4,4)))
void pool_kernel(
    const float* __restrict__ H, const int* __restrict__ batch,
    const float* __restrict__ SGWT, const float* __restrict__ w1g,
    const float* __restrict__ b1, const float* __restrict__ w2,
    const float* __restrict__ b2, float* __restrict__ wsAcc, int N)
{
  __shared__ float w1L[4096];                    // 16 KB
  __shared__ __align__(16) float TL[64*20];      // 5.1 KB (T rows, stride 20)
  __shared__ float eL[64];
  __shared__ int   gL[64];
  __shared__ float b1L[64];
  __shared__ float w2L[64];

  const int tid = threadIdx.x;
  const int n0 = blockIdx.x * NPB;
  const int iq = tid & 3;
  const int nq = tid >> 2;

  // ---- staging ----
  for (int i=tid;i<4096;i+=256) w1L[i]=w1g[i];
  for (int i=tid;i<1024;i+=256){            // T: 64 nodes x 16 floats
    int nl = i & 63, r = i >> 6;
    int nd = n0 + nl;
    TL[nl*20 + r] = (nd < N) ? SGWT[(size_t)(10+r)*N + nd] : 0.0f;
  }
  if (tid < 64){
    int nd = n0 + tid;
    gL[tid] = batch[nd < N ? nd : (N-1)];
    eL[tid] = 0.0f;
    b1L[tid]=b1[tid]; w2L[tid]=w2[tid];
  }
  __syncthreads();

  const int node = n0 + nq;
  const bool valid = node < N;
  const float b2v = b2[0];

  // ---- pass A + MLP (quad layout) ----
  if (valid){
    const float* Hn = H + (size_t)node*256;
    float Wq[10];
    #pragma unroll
    for (int r=0;r<10;++r) Wq[r]=SGWT[(size_t)r*N + node];
    float Wm[4][4];
    Wm[0][0]=Wq[0]; Wm[0][1]=Wm[1][0]=Wq[1]; Wm[0][2]=Wm[2][0]=Wq[2]; Wm[0][3]=Wm[3][0]=Wq[3];
    Wm[1][1]=Wq[4]; Wm[1][2]=Wm[2][1]=Wq[5]; Wm[1][3]=Wm[3][1]=Wq[6];
    Wm[2][2]=Wq[7]; Wm[2][3]=Wm[3][2]=Wq[8]; Wm[3][3]=Wq[9];
    float e;
    SCORE_BODY(Hn, Wm, w1L, b1L, w2L, b2v, iq, e)
    if (iq==0) eL[nq] = e;
  }
  __syncthreads();

  // ---- pass B (channel layout, register accumulation) ----
  {
    const int c    = tid & 63;          // channel
    const int base = (tid >> 6) * 16;   // this wave's 16-node run
    float a0=0.0f,a1=0.0f,a2=0.0f,a3=0.0f,aE=0.0f;
    int gcur = gL[base];
    for (int i=0;i<16;++i){
      int nl = base + i;
      int nd = n0 + nl;
      if (nd >= N) break;               // wave-uniform
      int g = gL[nl];
      if (g != gcur){                   // wave-uniform boundary flush
        float* wp = wsAcc + (size_t)gcur*WSG_STRIDE;
        atomicAdd(wp +        c, a0);
        atomicAdd(wp +  64 +  c, a1);
        atomicAdd(wp + 128 +  c, a2);
        atomicAdd(wp + 192 +  c, a3);
        if (c==0) atomicAdd(wp + 256, aE);
        a0=a1=a2=a3=aE=0.0f; gcur=g;
      }
      float e = eL[nl];                 // broadcast
      const float* Hn2 = H + (size_t)nd*256;
      float h0 = Hn2[       c];
      float h1 = Hn2[ 64 +  c];
      float h2 = Hn2[128 +  c];
      float h3 = Hn2[192 +  c];
      const float* t = TL + nl*20;
      float4 T0 = *(const float4*)(t);      // broadcast b128
      float4 T1 = *(const float4*)(t+4);
      float4 T2 = *(const float4*)(t+8);
      float4 T3 = *(const float4*)(t+12);
      a0 += e*(T0.x*h0 + T0.y*h1 + T0.z*h2 + T0.w*h3);
      a1 += e*(T1.x*h0 + T1.y*h1 + T1.z*h2 + T1.w*h3);
      a2 += e*(T2.x*h0 + T2.y*h1 + T2.z*h2 + T2.w*h3);
      a3 += e*(T3.x*h0 + T3.y*h1 + T3.z*h2 + T3.w*h3);
      aE += e;
    }
    float* wp = wsAcc + (size_t)gcur*WSG_STRIDE;
    atomicAdd(wp +        c, a0);
    atomicAdd(wp +  64 +  c, a1);
    atomicAdd(wp + 128 +  c, a2);
    atomicAdd(wp + 192 +  c, a3);
    if (c==0) atomicAdd(wp + 256, aE);
  }
}

// ============ FUSED FALLBACK (round-2-style, 1.06 MB ws) ============
__global__ __launch_bounds__(256, 3) __attribute__((amdgpu_waves_per_eu(3,3)))
void node_kernel(
    const float* __restrict__ H, const int* __restrict__ batch,
    const float* __restrict__ anchor, const float* __restrict__ w1g,
    const float* __restrict__ b1, const float* __restrict__ w2,
    const float* __restrict__ b2, float* __restrict__ wsAcc, int N)
{
  __shared__ float w1L[4096];
  __shared__ float accL[MAXG*ACC_STRIDE];
  __shared__ float aL[256];
  __shared__ float b1L[64];
  __shared__ float w2L[64];

  const int tid = threadIdx.x;
  const int n0 = blockIdx.x * NPB;
  const int iq = tid & 3;
  const int nq = tid >> 2;
  const int lane = tid & 63;

  for (int i=tid;i<4096;i+=256) w1L[i]=w1g[i];
  aL[tid]=anchor[tid];
  if (tid < 64){ b1L[tid]=b1[tid]; w2L[tid]=w2[tid]; }
  for (int i=tid;i<MAXG*ACC_STRIDE;i+=256) accL[i]=0.0f;
  __syncthreads();

  const int node = n0 + nq;
  const bool valid = node < N;

  float S[10], G[16];
  #pragma unroll
  for (int r=0;r<10;++r) S[r]=0.0f;
  #pragma unroll
  for (int r=0;r<16;++r) G[r]=0.0f;
  if (valid){
    const float* Hn = H + (size_t)node*256;
    PHASE1(Hn, aL, S, G, iq)
  }
  #pragma unroll
  for (int r=0;r<10;++r){ S[r]+=__shfl_xor(S[r],1); S[r]+=__shfl_xor(S[r],2); }
  #pragma unroll
  for (int r=0;r<16;++r){ G[r]+=__shfl_xor(G[r],1); G[r]+=__shfl_xor(G[r],2); }

  const int srcOwn = (lane & 15) << 2;
  float Sd[10], Gd[16];
  #pragma unroll
  for (int r=0;r<10;++r) Sd[r]=__shfl(S[r], srcOwn);
  #pragma unroll
  for (int r=0;r<16;++r) Gd[r]=__shfl(G[r], srcOwn);

  float Wp[10], Tm[16];
  #pragma unroll
  for (int r=0;r<10;++r) Wp[r]=0.0f;
  #pragma unroll
  for (int r=0;r<16;++r) Tm[r]=0.0f;
  {
    const int node2 = n0 + ((tid>>6)<<4) + (lane & 15);
    if (lane < 16 && node2 < N){
      phase2_body(Sd, Gd, Wp, Tm);
    }
  }

  const float b2v = b2[0];
  const int gFirst = batch[n0];
  const int srcNode = lane >> 2;

  float Wq[10], Tq[16];
  #pragma unroll
  for (int r=0;r<10;++r) Wq[r]=__shfl(Wp[r], srcNode);
  #pragma unroll
  for (int r=0;r<16;++r) Tq[r]=__shfl(Tm[r], srcNode);

  if (valid){
    const float* Hn = H + (size_t)node*256;
    float Wm[4][4];
    Wm[0][0]=Wq[0]; Wm[0][1]=Wm[1][0]=Wq[1]; Wm[0][2]=Wm[2][0]=Wq[2]; Wm[0][3]=Wm[3][0]=Wq[3];
    Wm[1][1]=Wq[4]; Wm[1][2]=Wm[2][1]=Wq[5]; Wm[1][3]=Wm[3][1]=Wq[6];
    Wm[2][2]=Wq[7]; Wm[2][3]=Wm[3][2]=Wq[8]; Wm[3][3]=Wq[9];
    float e;
    SCORE_BODY(Hn, Wm, w1L, b1L, w2L, b2v, iq, e)

    asm volatile("" ::: "memory");
    float T[4][4];
    #pragma unroll
    for (int d=0;d<4;++d){
      #pragma unroll
      for (int e2=0;e2<4;++e2) T[d][e2]=Tq[4*d+e2];
    }
    int g  = batch[node];
    int gl = g - gFirst;
    if (gl < MAXG){
      ZPASS(accL + gl*ACC_STRIDE, Hn, T, e, nq, iq)
      if (iq==0) atomicAdd(accL + gl*ACC_STRIDE + 256, e);
    } else {
      ZPASS(wsAcc + (size_t)g*WSG_STRIDE, Hn, T, e, nq, iq)
      if (iq==0) atomicAdd(wsAcc + (size_t)g*WSG_STRIDE + 256, e);
    }
  }
  __syncthreads();

  {
    int lastIdx = n0+NPB-1 < N ? n0+NPB-1 : N-1;
    int gLast = batch[lastIdx];
    int ngl = gLast - gFirst + 1; if (ngl > MAXG) ngl = MAXG;
    for (int idx=tid; idx<ngl*ACC_STRIDE; idx+=256){
      int gl = idx / ACC_STRIDE;
      int sl = idx - gl*ACC_STRIDE;
      float v = accL[idx];
      if (v != 0.0f) atomicAdd(wsAcc + (size_t)(gFirst+gl)*WSG_STRIDE + sl, v);
    }
  }
}

// ---------------- per-graph MLP + LayerNorm + reduce ----------------
__global__ __launch_bounds__(256) void finalize_kernel(
    const float* __restrict__ wsAcc, const float* __restrict__ token,
    const float* __restrict__ wc1, const float* __restrict__ bc1,
    const float* __restrict__ wc2, const float* __restrict__ bc2,
    const float* __restrict__ lng, const float* __restrict__ lnb,
    float* __restrict__ out)
{
  __shared__ float comb[4][128];
  __shared__ float hcL[4][64];
  __shared__ float upsq[4][64];
  const int g = blockIdx.x, tid = threadIdx.x;
  const int d = tid >> 6, k = tid & 63;
  const float* wsg = wsAcc + (size_t)g*WSG_STRIDE;
  float denom = wsg[256];
  float inv = (denom != 0.0f) ? 1.0f/denom : 0.0f;
  for (int i=tid;i<512;i+=256){
    int dd=i>>7, j=i&127;
    comb[dd][j] = (j<64) ? token[dd*64+j] : wsg[dd*64+(j-64)]*inv;
  }
  __syncthreads();
  float acc = bc1[k];
  for (int j=0;j<128;++j) acc += comb[d][j]*wc1[j*64+k];
  hcL[d][k] = gelu_exact(acc);
  __syncthreads();
  float acc2 = bc2[k];
  for (int j=0;j<64;++j) acc2 += hcL[d][j]*wc2[j*64+k];
  float s1 = acc2, s2 = acc2*acc2;
  #pragma unroll
  for (int m=1;m<64;m<<=1){ s1 += __shfl_xor(s1,m); s2 += __shfl_xor(s2,m); }
  float mu  = s1*(1.0f/64.0f);
  float var = s2*(1.0f/64.0f) - mu*mu;
  float up = (acc2 - mu)*(1.0f/sqrtf(var + 1e-5f))*lng[k] + lnb[k];
  upsq[d][k] = up*up;
  __syncthreads();
  if (tid < 64)
    out[(size_t)g*64 + tid] = upsq[0][tid]+upsq[1][tid]+upsq[2][tid]+upsq[3][tid];
}

extern "C" void kernel_launch(void* const* d_in, const int* in_sizes, int n_in,
                              void* d_out, int out_size, void* d_ws, size_t ws_size,
                              hipStream_t stream) {
  (void)n_in;
  const float* H      = (const float*)d_in[0];
  const int*   batch  = (const int*)  d_in[1];
  const float* anchor = (const float*)d_in[3];
  const float* w1     = (const float*)d_in[4];
  const float* b1     = (const float*)d_in[5];
  const float* w2     = (const float*)d_in[6];
  const float* b2     = (const float*)d_in[7];
  const float* token  = (const float*)d_in[8];
  const float* wc1    = (const float*)d_in[9];
  const float* bc1    = (const float*)d_in[10];
  const float* wc2    = (const float*)d_in[11];
  const float* bc2    = (const float*)d_in[12];
  const float* ln_g   = (const float*)d_in[13];
  const float* ln_b   = (const float*)d_in[14];
  float* out = (float*)d_out;

  const int N = in_sizes[0] / 256;   // nodes
  const int B = out_size / 64;       // graphs
  const int nb = (N + NPB - 1)/NPB;

  float* wsAcc = (float*)d_ws;       // B*WSG_STRIDE floats
  const size_t needBase  = (size_t)B*WSG_STRIDE*sizeof(float);
  const size_t needSplit = needBase + (size_t)26*N*sizeof(float);

  hipMemsetAsync(wsAcc, 0, needBase, stream);

  if (ws_size >= needSplit){
    // split path (round-9 best-verified): sg -> svd(uniform, sole-content)
    // -> pool(passA+MLP+regacc-passB)
    float* SGWT = wsAcc + (size_t)B*WSG_STRIDE;   // 26*N floats: S||G -> W||T
    const int nsvd = (N + 255)/256;
    sg_kernel<<<nb, 256, 0, stream>>>(H, anchor, SGWT, N);
    svd_kernel<<<nsvd, 256, 0, stream>>>(SGWT, N);
    pool_kernel<<<nb, 256, 0, stream>>>(H, batch, SGWT, w1, b1, w2, b2, wsAcc, N);
  } else {
    // fused fallback: fits in B*WSG_STRIDE floats
    node_kernel<<<nb, 256, 0, stream>>>(H, batch, anchor, w1, b1, w2, b2, wsAcc, N);
  }
  finalize_kernel<<<B, 256, 0, stream>>>(wsAcc, token, wc1, bc1, wc2, bc2, ln_g, ln_b, out);
}

// Round 12
// 313.283 us; speedup vs baseline: 1.0481x; 1.0034x over previous
//
#include <hip/hip_runtime.h>
#include <math.h>

#define WSG_STRIDE 260    // per-graph accum: 256 num + 1 denom (+pad)
#define ACC_STRIDE 257    // per-graph slots in LDS accumulator (fallback only)
#define MAXG 4            // fallback kernel only
#define NPB 64            // nodes per block (pool/fallback)

__device__ __forceinline__ float dot4f(float4 a, float4 b){
  return a.x*b.x + a.y*b.y + a.z*b.z + a.w*b.w;
}
__device__ __forceinline__ float gelu_exact(float x){
  return 0.5f*x*(1.0f+erff(x*0.70710678118654752440f));
}
__device__ __forceinline__ void mm44(float o[4][4], const float a[4][4], const float b[4][4]){
  #pragma unroll
  for (int i=0;i<4;++i){
    #pragma unroll
    for (int j=0;j<4;++j)
      o[i][j] = a[i][0]*b[0][j] + a[i][1]*b[1][j] + a[i][2]*b[2][j] + a[i][3]*b[3][j];
  }
}

template<int P,int Q,int K1,int K2>
__device__ __forceinline__ void jrot(float a[4][4], float V[4][4]){
  float apq = a[P][Q];
  if (fabsf(apq) > 1e-30f){
    float app=a[P][P], aqq=a[Q][Q];
    float tau=(aqq-app)/(2.0f*apq);
    float t=copysignf(1.0f,tau)/(fabsf(tau)+sqrtf(1.0f+tau*tau));
    float c=1.0f/sqrtf(1.0f+t*t), s=t*c;
    float a1p=a[K1][P], a1q=a[K1][Q];
    a[K1][P]=c*a1p-s*a1q; a[P][K1]=a[K1][P];
    a[K1][Q]=s*a1p+c*a1q; a[Q][K1]=a[K1][Q];
    float a2p=a[K2][P], a2q=a[K2][Q];
    a[K2][P]=c*a2p-s*a2q; a[P][K2]=a[K2][P];
    a[K2][Q]=s*a2p+c*a2q; a[Q][K2]=a[K2][Q];
    a[P][P]=app-t*apq; a[Q][Q]=aqq+t*apq; a[P][Q]=0.0f; a[Q][P]=0.0f;
    #pragma unroll
    for (int r=0;r<4;++r){ float vp=V[r][P], vq=V[r][Q]; V[r][P]=c*vp-s*vq; V[r][Q]=s*vp+c*vq; }
  }
}

__device__ __forceinline__ void jacobi4(float a[4][4], float V[4][4], int sweeps){
  #pragma unroll
  for (int i=0;i<4;++i){
    #pragma unroll
    for (int j=0;j<4;++j) V[i][j] = (i==j)?1.0f:0.0f;
  }
  for (int sw=0; sw<sweeps; ++sw){
    jrot<0,1,2,3>(a,V); jrot<0,2,1,3>(a,V); jrot<0,3,1,2>(a,V);
    jrot<1,2,0,3>(a,V); jrot<1,3,0,2>(a,V); jrot<2,3,0,1>(a,V);
  }
}

__device__ __forceinline__ float det4(const float V[4][4]){
  float s0 = V[0][0]*V[1][1] - V[0][1]*V[1][0];
  float s1 = V[0][0]*V[1][2] - V[0][2]*V[1][0];
  float s2 = V[0][0]*V[1][3] - V[0][3]*V[1][0];
  float s3 = V[0][1]*V[1][2] - V[0][2]*V[1][1];
  float s4 = V[0][1]*V[1][3] - V[0][3]*V[1][1];
  float s5 = V[0][2]*V[1][3] - V[0][3]*V[1][2];
  float c5 = V[2][2]*V[3][3] - V[2][3]*V[3][2];
  float c4 = V[2][1]*V[3][3] - V[2][3]*V[3][1];
  float c3 = V[2][1]*V[3][2] - V[2][2]*V[3][1];
  float c2 = V[2][0]*V[3][3] - V[2][3]*V[3][0];
  float c1 = V[2][0]*V[3][2] - V[2][2]*V[3][0];
  float c0 = V[2][0]*V[3][1] - V[2][1]*V[3][0];
  return s0*c5 - s1*c4 + s2*c3 + s3*c2 - s4*c1 + s5*c0;
}

// ============ device-side phase-2 body (shared) ============
// ALLOCATOR RULE (measured, rounds 1/2/4/6/7/8/10): this body may ONLY live
// in a kernel where it is the sole content, one node per thread, uniform
// control flow, (256,3)+wpe(3,3). Any co-residence with streaming phases
// or divergent guards -> hipcc compresses VGPRs below budget and spills
// the whole live set to scratch (65-130MB WRITE_SIZE signature).
__device__ __forceinline__ void phase2_body(const float Sd[10], const float Gd[16],
                                            float Wp[10], float Tout[16]){
  float a00=Sd[0]+1e-4f, a01=Sd[1], a02=Sd[2], a03=Sd[3];
  float a11=Sd[4]+1e-4f, a12=Sd[5], a13=Sd[6];
  float a22=Sd[7]+1e-4f, a23=Sd[8], a33=Sd[9]+1e-4f;
  float Gm[4][4];
  #pragma unroll
  for (int d=0;d<4;++d){
    #pragma unroll
    for (int f=0;f<4;++f) Gm[d][f]=Gd[4*d+f];
  }
  float cs = 0.4f*(a00+a11+a22+a33);
  float rc = 1.0f/cs;
  float Y[4][4], Z[4][4];
  Y[0][0]=a00*rc; Y[0][1]=Y[1][0]=a01*rc; Y[0][2]=Y[2][0]=a02*rc; Y[0][3]=Y[3][0]=a03*rc;
  Y[1][1]=a11*rc; Y[1][2]=Y[2][1]=a12*rc; Y[1][3]=Y[3][1]=a13*rc;
  Y[2][2]=a22*rc; Y[2][3]=Y[3][2]=a23*rc; Y[3][3]=a33*rc;
  #pragma unroll
  for (int i=0;i<4;++i){
    #pragma unroll
    for (int j=0;j<4;++j) Z[i][j]=(i==j)?1.0f:0.0f;
  }
  #pragma unroll
  for (int it=0; it<8; ++it){
    float P[4][4], Y2[4][4], Z2[4][4];
    mm44(P, Z, Y);
    #pragma unroll
    for (int i=0;i<4;++i){
      #pragma unroll
      for (int j=0;j<4;++j) P[i][j] = (i==j) ? 1.5f-0.5f*P[i][j] : -0.5f*P[i][j];
    }
    mm44(Y2, Y, P);
    mm44(Z2, P, Z);
    #pragma unroll
    for (int i=0;i<4;++i){
      #pragma unroll
      for (int j=0;j<4;++j){ Y[i][j]=Y2[i][j]; Z[i][j]=Z2[i][j]; }
    }
  }
  float rsc = rsqrtf(cs);
  float Wm[4][4];
  #pragma unroll
  for (int i=0;i<4;++i){
    #pragma unroll
    for (int j=0;j<4;++j) Wm[i][j] = Z[i][j]*rsc;
  }
  Wp[0]=Wm[0][0]; Wp[1]=Wm[0][1]; Wp[2]=Wm[0][2]; Wp[3]=Wm[0][3];
  Wp[4]=Wm[1][1]; Wp[5]=Wm[1][2]; Wp[6]=Wm[1][3];
  Wp[7]=Wm[2][2]; Wp[8]=Wm[2][3]; Wp[9]=Wm[3][3];
  float M[4][4];
  mm44(M, Gm, Wm);
  float A2[4][4];
  #pragma unroll
  for (int i=0;i<4;++i){
    #pragma unroll
    for (int j=0;j<4;++j)
      A2[i][j] = M[0][i]*M[0][j] + M[1][i]*M[1][j] + M[2][i]*M[2][j] + M[3][i]*M[3][j];
  }
  float V2[4][4];
  jacobi4(A2, V2, 4);
  float mu[4];
  #pragma unroll
  for (int i=0;i<4;++i) mu[i]=A2[i][i];
  #define CSW(I,J) if (mu[I] < mu[J]) { float tw; \
    tw=mu[I]; mu[I]=mu[J]; mu[J]=tw; \
    tw=V2[0][I]; V2[0][I]=V2[0][J]; V2[0][J]=tw; \
    tw=V2[1][I]; V2[1][I]=V2[1][J]; V2[1][J]=tw; \
    tw=V2[2][I]; V2[2][I]=V2[2][J]; V2[2][J]=tw; \
    tw=V2[3][I]; V2[3][I]=V2[3][J]; V2[3][J]=tw; }
  CSW(0,1) CSW(2,3) CSW(0,2) CSW(1,3) CSW(1,2)
  #undef CSW
  float u0[4],u1[4],u2[4];
  #pragma unroll
  for (int d=0;d<4;++d){
    u0[d]=M[d][0]*V2[0][0]+M[d][1]*V2[1][0]+M[d][2]*V2[2][0]+M[d][3]*V2[3][0];
    u1[d]=M[d][0]*V2[0][1]+M[d][1]*V2[1][1]+M[d][2]*V2[2][1]+M[d][3]*V2[3][1];
    u2[d]=M[d][0]*V2[0][2]+M[d][1]*V2[1][2]+M[d][2]*V2[2][2]+M[d][3]*V2[3][2];
  }
  {
    float dd = u0[0]*u0[0]+u0[1]*u0[1]+u0[2]*u0[2]+u0[3]*u0[3];
    float in0 = 1.0f/sqrtf(fmaxf(dd,1e-30f));
    #pragma unroll
    for (int d=0;d<4;++d) u0[d]*=in0;
    float p01 = u0[0]*u1[0]+u0[1]*u1[1]+u0[2]*u1[2]+u0[3]*u1[3];
    #pragma unroll
    for (int d=0;d<4;++d) u1[d]-=p01*u0[d];
    dd = u1[0]*u1[0]+u1[1]*u1[1]+u1[2]*u1[2]+u1[3]*u1[3];
    float in1 = 1.0f/sqrtf(fmaxf(dd,1e-30f));
    #pragma unroll
    for (int d=0;d<4;++d) u1[d]*=in1;
    float p02 = u0[0]*u2[0]+u0[1]*u2[1]+u0[2]*u2[2]+u0[3]*u2[3];
    float p12 = u1[0]*u2[0]+u1[1]*u2[1]+u1[2]*u2[2]+u1[3]*u2[3];
    #pragma unroll
    for (int d=0;d<4;++d) u2[d]-=p02*u0[d]+p12*u1[d];
    dd = u2[0]*u2[0]+u2[1]*u2[1]+u2[2]*u2[2]+u2[3]*u2[3];
    float in2 = 1.0f/sqrtf(fmaxf(dd,1e-30f));
    #pragma unroll
    for (int d=0;d<4;++d) u2[d]*=in2;
  }
  #define D3(p,q,r) (u0[p]*(u1[q]*u2[r]-u1[r]*u2[q]) - u1[p]*(u0[q]*u2[r]-u0[r]*u2[q]) + u2[p]*(u0[q]*u1[r]-u0[r]*u1[q]))
  float t3[4];
  t3[0] = -D3(1,2,3); t3[1] = D3(0,2,3); t3[2] = -D3(0,1,3); t3[3] = D3(0,1,2);
  #undef D3
  float dl = (det4(V2) >= 0.0f) ? 1.0f : -1.0f;
  float R[4][4];
  #pragma unroll
  for (int d=0;d<4;++d){
    #pragma unroll
    for (int e=0;e<4;++e)
      R[d][e] = u0[d]*V2[e][0] + u1[d]*V2[e][1] + u2[d]*V2[e][2] + dl*t3[d]*V2[e][3];
  }
  float Wr[4][4];
  Wr[0][0]=Wp[0]; Wr[0][1]=Wr[1][0]=Wp[1]; Wr[0][2]=Wr[2][0]=Wp[2]; Wr[0][3]=Wr[3][0]=Wp[3];
  Wr[1][1]=Wp[4]; Wr[1][2]=Wr[2][1]=Wp[5]; Wr[1][3]=Wr[3][1]=Wp[6];
  Wr[2][2]=Wp[7]; Wr[2][3]=Wr[3][2]=Wp[8]; Wr[3][3]=Wp[9];
  float T[4][4];
  mm44(T, R, Wr);
  #pragma unroll
  for (int d=0;d<4;++d){
    #pragma unroll
    for (int ee=0;ee<4;++ee) Tout[4*d+ee]=T[d][ee];
  }
}

// shared phase-1 body
#define PHASE1(HN, AL, SARR, GARR, IQ) { \
  _Pragma("unroll") \
  for (int j=0;j<4;++j){ \
    float4 h0 = *(const float4*)((HN) + 0*64 + j*16 + (IQ)*4); \
    float4 h1v= *(const float4*)((HN) + 1*64 + j*16 + (IQ)*4); \
    float4 h2 = *(const float4*)((HN) + 2*64 + j*16 + (IQ)*4); \
    float4 h3 = *(const float4*)((HN) + 3*64 + j*16 + (IQ)*4); \
    float4 a0 = *(const float4*)((AL) + 0*64 + j*16 + (IQ)*4); \
    float4 a1 = *(const float4*)((AL) + 1*64 + j*16 + (IQ)*4); \
    float4 a2 = *(const float4*)((AL) + 2*64 + j*16 + (IQ)*4); \
    float4 a3 = *(const float4*)((AL) + 3*64 + j*16 + (IQ)*4); \
    SARR[0]+=dot4f(h0,h0); SARR[1]+=dot4f(h0,h1v); SARR[2]+=dot4f(h0,h2); SARR[3]+=dot4f(h0,h3); \
    SARR[4]+=dot4f(h1v,h1v); SARR[5]+=dot4f(h1v,h2); SARR[6]+=dot4f(h1v,h3); \
    SARR[7]+=dot4f(h2,h2); SARR[8]+=dot4f(h2,h3); SARR[9]+=dot4f(h3,h3); \
    GARR[0]+=dot4f(a0,h0);  GARR[1]+=dot4f(a0,h1v);  GARR[2]+=dot4f(a0,h2);  GARR[3]+=dot4f(a0,h3); \
    GARR[4]+=dot4f(a1,h0);  GARR[5]+=dot4f(a1,h1v);  GARR[6]+=dot4f(a1,h2);  GARR[7]+=dot4f(a1,h3); \
    GARR[8]+=dot4f(a2,h0);  GARR[9]+=dot4f(a2,h1v);  GARR[10]+=dot4f(a2,h2); GARR[11]+=dot4f(a2,h3); \
    GARR[12]+=dot4f(a3,h0); GARR[13]+=dot4f(a3,h1v); GARR[14]+=dot4f(a3,h2); GARR[15]+=dot4f(a3,h3); \
  } }

// fallback-only pass-B macro (LDS atomics, staggered)
#define ZPASS(ACCPTR, HNPTR, TMAT, EV, NQ, IQ) { \
  float* accp = (ACCPTR); \
  _Pragma("unroll") \
  for (int j=0;j<4;++j){ \
    float4 t0 = *(const float4*)((HNPTR) + 0*64 + j*16 + (IQ)*4); \
    float4 t1 = *(const float4*)((HNPTR) + 1*64 + j*16 + (IQ)*4); \
    float4 t2 = *(const float4*)((HNPTR) + 2*64 + j*16 + (IQ)*4); \
    float4 t3 = *(const float4*)((HNPTR) + 3*64 + j*16 + (IQ)*4); \
    float z0[4], z1[4], z2[4], z3[4]; \
    _Pragma("unroll") \
    for (int c=0;c<4;++c){ \
      float x0 = (c==0)?t0.x:(c==1)?t0.y:(c==2)?t0.z:t0.w; \
      float x1 = (c==0)?t1.x:(c==1)?t1.y:(c==2)?t1.z:t1.w; \
      float x2 = (c==0)?t2.x:(c==1)?t2.y:(c==2)?t2.z:t2.w; \
      float x3 = (c==0)?t3.x:(c==1)?t3.y:(c==2)?t3.z:t3.w; \
      z0[c] = TMAT[0][0]*x0+TMAT[0][1]*x1+TMAT[0][2]*x2+TMAT[0][3]*x3; \
      z1[c] = TMAT[1][0]*x0+TMAT[1][1]*x1+TMAT[1][2]*x2+TMAT[1][3]*x3; \
      z2[c] = TMAT[2][0]*x0+TMAT[2][1]*x1+TMAT[2][2]*x2+TMAT[2][3]*x3; \
      z3[c] = TMAT[3][0]*x0+TMAT[3][1]*x1+TMAT[3][2]*x2+TMAT[3][3]*x3; \
    } \
    _Pragma("unroll") \
    for (int dd=0;dd<4;++dd){ \
      int dsel = ((NQ) + dd) & 3; \
      _Pragma("unroll") \
      for (int c=0;c<4;++c){ \
        int csel = (((NQ)>>2) + c) & 3; \
        float zv = \
          (dsel==0)?((csel==0)?z0[0]:(csel==1)?z0[1]:(csel==2)?z0[2]:z0[3]): \
          (dsel==1)?((csel==0)?z1[0]:(csel==1)?z1[1]:(csel==2)?z1[2]:z1[3]): \
          (dsel==2)?((csel==0)?z2[0]:(csel==1)?z2[1]:(csel==2)?z2[2]:z2[3]): \
                    ((csel==0)?z3[0]:(csel==1)?z3[1]:(csel==2)?z3[2]:z3[3]); \
        atomicAdd(accp + dsel*64 + 16*j + 4*(IQ) + csel, (EV)*zv); \
      } \
    } \
  } }

// shared score body: pass A (u) + MLP -> e
#define SCORE_BODY(HN, WMAT, W1L, B1L, W2L, B2V, IQ, EOUT) { \
  float u[16]; \
  _Pragma("unroll") \
  for (int j=0;j<4;++j){ \
    float4 t0 = *(const float4*)((HN) + 0*64 + j*16 + (IQ)*4); \
    float4 t1 = *(const float4*)((HN) + 1*64 + j*16 + (IQ)*4); \
    float4 t2 = *(const float4*)((HN) + 2*64 + j*16 + (IQ)*4); \
    float4 t3 = *(const float4*)((HN) + 3*64 + j*16 + (IQ)*4); \
    _Pragma("unroll") \
    for (int c=0;c<4;++c){ \
      float x0 = (c==0)?t0.x:(c==1)?t0.y:(c==2)?t0.z:t0.w; \
      float x1 = (c==0)?t1.x:(c==1)?t1.y:(c==2)?t1.z:t1.w; \
      float x2 = (c==0)?t2.x:(c==1)?t2.y:(c==2)?t2.z:t2.w; \
      float x3 = (c==0)?t3.x:(c==1)?t3.y:(c==2)?t3.z:t3.w; \
      float w0 = WMAT[0][0]*x0+WMAT[0][1]*x1+WMAT[0][2]*x2+WMAT[0][3]*x3; \
      float w1v= WMAT[1][0]*x0+WMAT[1][1]*x1+WMAT[1][2]*x2+WMAT[1][3]*x3; \
      float w2v= WMAT[2][0]*x0+WMAT[2][1]*x1+WMAT[2][2]*x2+WMAT[2][3]*x3; \
      float w3 = WMAT[3][0]*x0+WMAT[3][1]*x1+WMAT[3][2]*x2+WMAT[3][3]*x3; \
      u[4*j+c] = w0*w0+w1v*w1v+w2v*w2v+w3*w3; \
    } \
  } \
  float h1[16]; \
  _Pragma("unroll") \
  for (int kk=0;kk<16;++kk) h1[kk]=B1L[(IQ)*16+kk]; \
  for (int m=0;m<4;++m){ \
    int qq = (IQ) ^ m; \
    _Pragma("unroll") \
    for (int jl=0;jl<16;++jl){ \
      float uu = __shfl_xor(u[jl], m); \
      int c = 16*(jl>>2) + 4*qq + (jl&3); \
      const float* wr = W1L + c*64 + (IQ)*16; \
      float4 wA=*(const float4*)(wr); \
      float4 wB=*(const float4*)(wr+4); \
      float4 wC=*(const float4*)(wr+8); \
      float4 wD=*(const float4*)(wr+12); \
      h1[0]+=uu*wA.x; h1[1]+=uu*wA.y; h1[2]+=uu*wA.z; h1[3]+=uu*wA.w; \
      h1[4]+=uu*wB.x; h1[5]+=uu*wB.y; h1[6]+=uu*wB.z; h1[7]+=uu*wB.w; \
      h1[8]+=uu*wC.x; h1[9]+=uu*wC.y; h1[10]+=uu*wC.z; h1[11]+=uu*wC.w; \
      h1[12]+=uu*wD.x; h1[13]+=uu*wD.y; h1[14]+=uu*wD.z; h1[15]+=uu*wD.w; \
    } \
  } \
  float sp = 0.0f; \
  _Pragma("unroll") \
  for (int kk=0;kk<16;++kk) sp += gelu_exact(h1[kk]) * W2L[(IQ)*16+kk]; \
  sp += __shfl_xor(sp,1); sp += __shfl_xor(sp,2); \
  EOUT = expf(sp + (B2V)); }

// ================= SPLIT PATH (needs 26*N extra ws floats) =================

// ---- K_sg: phase 1 (round-9 exact) + folded wsAcc zeroing (replaces the
// hipMemsetAsync dispatch: stream order guarantees completion before pool).
__global__ __launch_bounds__(256, 4) __attribute__((amdgpu_waves_per_eu(4,4)))
void sg_kernel(const float* __restrict__ H, const float* __restrict__ anchor,
               float* __restrict__ SGWT, float* __restrict__ wsAcc,
               int wsTotal, int N)
{
  __shared__ float aL[256];
  const int tid = threadIdx.x;
  const int n0 = blockIdx.x * NPB;
  const int iq = tid & 3;
  const int nq = tid >> 2;
  aL[tid] = anchor[tid];
  // folded memset: grid-stride zero of wsAcc (1.06MB over 2048 blocks)
  for (int i = blockIdx.x*256 + tid; i < wsTotal; i += gridDim.x*256)
    wsAcc[i] = 0.0f;
  __syncthreads();
  const int node = n0 + nq;
  if (node >= N) return;

  const float* Hn = H + (size_t)node*256;
  float S[10], G[16];
  #pragma unroll
  for (int r=0;r<10;++r) S[r]=0.0f;
  #pragma unroll
  for (int r=0;r<16;++r) G[r]=0.0f;
  PHASE1(Hn, aL, S, G, iq)
  #pragma unroll
  for (int r=0;r<10;++r){ S[r]+=__shfl_xor(S[r],1); S[r]+=__shfl_xor(S[r],2); }
  #pragma unroll
  for (int r=0;r<16;++r){ G[r]+=__shfl_xor(G[r],1); G[r]+=__shfl_xor(G[r],2); }
  if (iq==0){
    #pragma unroll
    for (int r=0;r<10;++r) SGWT[(size_t)r*N + node] = S[r];
    #pragma unroll
    for (int r=0;r<16;++r) SGWT[(size_t)(10+r)*N + node] = G[r];
  }
}

// ---- K_svd: phase 2 — SOLE content, one node/thread, uniform (round-9 exact)
__global__ __launch_bounds__(256, 3) __attribute__((amdgpu_waves_per_eu(3,3)))
void svd_kernel(float* __restrict__ SGWT, int N)
{
  const int node = blockIdx.x*256 + threadIdx.x;
  if (node >= N) return;
  float Sd[10], Gd[16];
  #pragma unroll
  for (int r=0;r<10;++r) Sd[r]=SGWT[(size_t)r*N + node];
  #pragma unroll
  for (int r=0;r<16;++r) Gd[r]=SGWT[(size_t)(10+r)*N + node];
  float Wp[10], T[16];
  phase2_body(Sd, Gd, Wp, T);
  #pragma unroll
  for (int r=0;r<10;++r) SGWT[(size_t)r*N + node] = Wp[r];
  #pragma unroll
  for (int r=0;r<16;++r) SGWT[(size_t)(10+r)*N + node] = T[r];
}

// ---- K_pool v2 (round-9 exact, measured ~66us): passA+MLP (quad layout)
// -> sync -> passB (channel layout, register accumulation, boundary-flush
// global atomics). ----
__global__ __launch_bounds__(256, 4) __attribute__((amdgpu_waves_per_eu(4,4)))
void pool_kernel(
    const float* __restrict__ H, const int* __restrict__ batch,
    const float* __restrict__ SGWT, const float* __restrict__ w1g,
    const float* __restrict__ b1, const float* __restrict__ w2,
    const float* __restrict__ b2, float* __restrict__ wsAcc, int N)
{
  __shared__ float w1L[4096];                    // 16 KB
  __shared__ __align__(16) float TL[64*20];      // 5.1 KB (T rows, stride 20)
  __shared__ float eL[64];
  __shared__ int   gL[64];
  __shared__ float b1L[64];
  __shared__ float w2L[64];

  const int tid = threadIdx.x;
  const int n0 = blockIdx.x * NPB;
  const int iq = tid & 3;
  const int nq = tid >> 2;

  // ---- staging ----
  for (int i=tid;i<4096;i+=256) w1L[i]=w1g[i];
  for (int i=tid;i<1024;i+=256){            // T: 64 nodes x 16 floats
    int nl = i & 63, r = i >> 6;
    int nd = n0 + nl;
    TL[nl*20 + r] = (nd < N) ? SGWT[(size_t)(10+r)*N + nd] : 0.0f;
  }
  if (tid < 64){
    int nd = n0 + tid;
    gL[tid] = batch[nd < N ? nd : (N-1)];
    eL[tid] = 0.0f;
    b1L[tid]=b1[tid]; w2L[tid]=w2[tid];
  }
  __syncthreads();

  const int node = n0 + nq;
  const bool valid = node < N;
  const float b2v = b2[0];

  // ---- pass A + MLP (quad layout) ----
  if (valid){
    const float* Hn = H + (size_t)node*256;
    float Wq[10];
    #pragma unroll
    for (int r=0;r<10;++r) Wq[r]=SGWT[(size_t)r*N + node];
    float Wm[4][4];
    Wm[0][0]=Wq[0]; Wm[0][1]=Wm[1][0]=Wq[1]; Wm[0][2]=Wm[2][0]=Wq[2]; Wm[0][3]=Wm[3][0]=Wq[3];
    Wm[1][1]=Wq[4]; Wm[1][2]=Wm[2][1]=Wq[5]; Wm[1][3]=Wm[3][1]=Wq[6];
    Wm[2][2]=Wq[7]; Wm[2][3]=Wm[3][2]=Wq[8]; Wm[3][3]=Wq[9];
    float e;
    SCORE_BODY(Hn, Wm, w1L, b1L, w2L, b2v, iq, e)
    if (iq==0) eL[nq] = e;
  }
  __syncthreads();

  // ---- pass B (channel layout, register accumulation) ----
  {
    const int c    = tid & 63;          // channel
    const int base = (tid >> 6) * 16;   // this wave's 16-node run
    float a0=0.0f,a1=0.0f,a2=0.0f,a3=0.0f,aE=0.0f;
    int gcur = gL[base];
    for (int i=0;i<16;++i){
      int nl = base + i;
      int nd = n0 + nl;
      if (nd >= N) break;               // wave-uniform
      int g = gL[nl];
      if (g != gcur){                   // wave-uniform boundary flush
        float* wp = wsAcc + (size_t)gcur*WSG_STRIDE;
        atomicAdd(wp +        c, a0);
        atomicAdd(wp +  64 +  c, a1);
        atomicAdd(wp + 128 +  c, a2);
        atomicAdd(wp + 192 +  c, a3);
        if (c==0) atomicAdd(wp + 256, aE);
        a0=a1=a2=a3=aE=0.0f; gcur=g;
      }
      float e = eL[nl];                 // broadcast
      const float* Hn2 = H + (size_t)nd*256;
      float h0 = Hn2[       c];
      float h1 = Hn2[ 64 +  c];
      float h2 = Hn2[128 +  c];
      float h3 = Hn2[192 +  c];
      const float* t = TL + nl*20;
      float4 T0 = *(const float4*)(t);      // broadcast b128
      float4 T1 = *(const float4*)(t+4);
      float4 T2 = *(const float4*)(t+8);
      float4 T3 = *(const float4*)(t+12);
      a0 += e*(T0.x*h0 + T0.y*h1 + T0.z*h2 + T0.w*h3);
      a1 += e*(T1.x*h0 + T1.y*h1 + T1.z*h2 + T1.w*h3);
      a2 += e*(T2.x*h0 + T2.y*h1 + T2.z*h2 + T2.w*h3);
      a3 += e*(T3.x*h0 + T3.y*h1 + T3.z*h2 + T3.w*h3);
      aE += e;
    }
    float* wp = wsAcc + (size_t)gcur*WSG_STRIDE;
    atomicAdd(wp +        c, a0);
    atomicAdd(wp +  64 +  c, a1);
    atomicAdd(wp + 128 +  c, a2);
    atomicAdd(wp + 192 +  c, a3);
    if (c==0) atomicAdd(wp + 256, aE);
  }
}

// ============ FUSED FALLBACK (round-2-style, 1.06 MB ws) ============
__global__ __launch_bounds__(256, 3) __attribute__((amdgpu_waves_per_eu(3,3)))
void node_kernel(
    const float* __restrict__ H, const int* __restrict__ batch,
    const float* __restrict__ anchor, const float* __restrict__ w1g,
    const float* __restrict__ b1, const float* __restrict__ w2,
    const float* __restrict__ b2, float* __restrict__ wsAcc, int N)
{
  __shared__ float w1L[4096];
  __shared__ float accL[MAXG*ACC_STRIDE];
  __shared__ float aL[256];
  __shared__ float b1L[64];
  __shared__ float w2L[64];

  const int tid = threadIdx.x;
  const int n0 = blockIdx.x * NPB;
  const int iq = tid & 3;
  const int nq = tid >> 2;
  const int lane = tid & 63;

  for (int i=tid;i<4096;i+=256) w1L[i]=w1g[i];
  aL[tid]=anchor[tid];
  if (tid < 64){ b1L[tid]=b1[tid]; w2L[tid]=w2[tid]; }
  for (int i=tid;i<MAXG*ACC_STRIDE;i+=256) accL[i]=0.0f;
  __syncthreads();

  const int node = n0 + nq;
  const bool valid = node < N;

  float S[10], G[16];
  #pragma unroll
  for (int r=0;r<10;++r) S[r]=0.0f;
  #pragma unroll
  for (int r=0;r<16;++r) G[r]=0.0f;
  if (valid){
    const float* Hn = H + (size_t)node*256;
    PHASE1(Hn, aL, S, G, iq)
  }
  #pragma unroll
  for (int r=0;r<10;++r){ S[r]+=__shfl_xor(S[r],1); S[r]+=__shfl_xor(S[r],2); }
  #pragma unroll
  for (int r=0;r<16;++r){ G[r]+=__shfl_xor(G[r],1); G[r]+=__shfl_xor(G[r],2); }

  const int srcOwn = (lane & 15) << 2;
  float Sd[10], Gd[16];
  #pragma unroll
  for (int r=0;r<10;++r) Sd[r]=__shfl(S[r], srcOwn);
  #pragma unroll
  for (int r=0;r<16;++r) Gd[r]=__shfl(G[r], srcOwn);

  float Wp[10], Tm[16];
  #pragma unroll
  for (int r=0;r<10;++r) Wp[r]=0.0f;
  #pragma unroll
  for (int r=0;r<16;++r) Tm[r]=0.0f;
  {
    const int node2 = n0 + ((tid>>6)<<4) + (lane & 15);
    if (lane < 16 && node2 < N){
      phase2_body(Sd, Gd, Wp, Tm);
    }
  }

  const float b2v = b2[0];
  const int gFirst = batch[n0];
  const int srcNode = lane >> 2;

  float Wq[10], Tq[16];
  #pragma unroll
  for (int r=0;r<10;++r) Wq[r]=__shfl(Wp[r], srcNode);
  #pragma unroll
  for (int r=0;r<16;++r) Tq[r]=__shfl(Tm[r], srcNode);

  if (valid){
    const float* Hn = H + (size_t)node*256;
    float Wm[4][4];
    Wm[0][0]=Wq[0]; Wm[0][1]=Wm[1][0]=Wq[1]; Wm[0][2]=Wm[2][0]=Wq[2]; Wm[0][3]=Wm[3][0]=Wq[3];
    Wm[1][1]=Wq[4]; Wm[1][2]=Wm[2][1]=Wq[5]; Wm[1][3]=Wm[3][1]=Wq[6];
    Wm[2][2]=Wq[7]; Wm[2][3]=Wm[3][2]=Wq[8]; Wm[3][3]=Wq[9];
    float e;
    SCORE_BODY(Hn, Wm, w1L, b1L, w2L, b2v, iq, e)

    asm volatile("" ::: "memory");
    float T[4][4];
    #pragma unroll
    for (int d=0;d<4;++d){
      #pragma unroll
      for (int e2=0;e2<4;++e2) T[d][e2]=Tq[4*d+e2];
    }
    int g  = batch[node];
    int gl = g - gFirst;
    if (gl < MAXG){
      ZPASS(accL + gl*ACC_STRIDE, Hn, T, e, nq, iq)
      if (iq==0) atomicAdd(accL + gl*ACC_STRIDE + 256, e);
    } else {
      ZPASS(wsAcc + (size_t)g*WSG_STRIDE, Hn, T, e, nq, iq)
      if (iq==0) atomicAdd(wsAcc + (size_t)g*WSG_STRIDE + 256, e);
    }
  }
  __syncthreads();

  {
    int lastIdx = n0+NPB-1 < N ? n0+NPB-1 : N-1;
    int gLast = batch[lastIdx];
    int ngl = gLast - gFirst + 1; if (ngl > MAXG) ngl = MAXG;
    for (int idx=tid; idx<ngl*ACC_STRIDE; idx+=256){
      int gl = idx / ACC_STRIDE;
      int sl = idx - gl*ACC_STRIDE;
      float v = accL[idx];
      if (v != 0.0f) atomicAdd(wsAcc + (size_t)(gFirst+gl)*WSG_STRIDE + sl, v);
    }
  }
}

// ---------------- per-graph MLP + LayerNorm + reduce ----------------
__global__ __launch_bounds__(256) void finalize_kernel(
    const float* __restrict__ wsAcc, const float* __restrict__ token,
    const float* __restrict__ wc1, const float* __restrict__ bc1,
    const float* __restrict__ wc2, const float* __restrict__ bc2,
    const float* __restrict__ lng, const float* __restrict__ lnb,
    float* __restrict__ out)
{
  __shared__ float comb[4][128];
  __shared__ float hcL[4][64];
  __shared__ float upsq[4][64];
  const int g = blockIdx.x, tid = threadIdx.x;
  const int d = tid >> 6, k = tid & 63;
  const float* wsg = wsAcc + (size_t)g*WSG_STRIDE;
  float denom = wsg[256];
  float inv = (denom != 0.0f) ? 1.0f/denom : 0.0f;
  for (int i=tid;i<512;i+=256){
    int dd=i>>7, j=i&127;
    comb[dd][j] = (j<64) ? token[dd*64+j] : wsg[dd*64+(j-64)]*inv;
  }
  __syncthreads();
  float acc = bc1[k];
  for (int j=0;j<128;++j) acc += comb[d][j]*wc1[j*64+k];
  hcL[d][k] = gelu_exact(acc);
  __syncthreads();
  float acc2 = bc2[k];
  for (int j=0;j<64;++j) acc2 += hcL[d][j]*wc2[j*64+k];
  float s1 = acc2, s2 = acc2*acc2;
  #pragma unroll
  for (int m=1;m<64;m<<=1){ s1 += __shfl_xor(s1,m); s2 += __shfl_xor(s2,m); }
  float mu  = s1*(1.0f/64.0f);
  float var = s2*(1.0f/64.0f) - mu*mu;
  float up = (acc2 - mu)*(1.0f/sqrtf(var + 1e-5f))*lng[k] + lnb[k];
  upsq[d][k] = up*up;
  __syncthreads();
  if (tid < 64)
    out[(size_t)g*64 + tid] = upsq[0][tid]+upsq[1][tid]+upsq[2][tid]+upsq[3][tid];
}

extern "C" void kernel_launch(void* const* d_in, const int* in_sizes, int n_in,
                              void* d_out, int out_size, void* d_ws, size_t ws_size,
                              hipStream_t stream) {
  (void)n_in;
  const float* H      = (const float*)d_in[0];
  const int*   batch  = (const int*)  d_in[1];
  const float* anchor = (const float*)d_in[3];
  const float* w1     = (const float*)d_in[4];
  const float* b1     = (const float*)d_in[5];
  const float* w2     = (const float*)d_in[6];
  const float* b2     = (const float*)d_in[7];
  const float* token  = (const float*)d_in[8];
  const float* wc1    = (const float*)d_in[9];
  const float* bc1    = (const float*)d_in[10];
  const float* wc2    = (const float*)d_in[11];
  const float* bc2    = (const float*)d_in[12];
  const float* ln_g   = (const float*)d_in[13];
  const float* ln_b   = (const float*)d_in[14];
  float* out = (float*)d_out;

  const int N = in_sizes[0] / 256;   // nodes
  const int B = out_size / 64;       // graphs
  const int nb = (N + NPB - 1)/NPB;

  float* wsAcc = (float*)d_ws;       // B*WSG_STRIDE floats
  const size_t needBase  = (size_t)B*WSG_STRIDE*sizeof(float);
  const size_t needSplit = needBase + (size_t)26*N*sizeof(float);

  if (ws_size >= needSplit){
    // split path (round-9 best-verified): sg(+folded memset) ->
    // svd(uniform, sole-content) -> pool(passA+MLP+regacc-passB)
    float* SGWT = wsAcc + (size_t)B*WSG_STRIDE;   // 26*N floats: S||G -> W||T
    const int nsvd = (N + 255)/256;
    const int wsTotal = B*WSG_STRIDE;
    sg_kernel<<<nb, 256, 0, stream>>>(H, anchor, SGWT, wsAcc, wsTotal, N);
    svd_kernel<<<nsvd, 256, 0, stream>>>(SGWT, N);
    pool_kernel<<<nb, 256, 0, stream>>>(H, batch, SGWT, w1, b1, w2, b2, wsAcc, N);
  } else {
    // fused fallback: fits in B*WSG_STRIDE floats (keeps its own memset)
    hipMemsetAsync(wsAcc, 0, needBase, stream);
    node_kernel<<<nb, 256, 0, stream>>>(H, batch, anchor, w1, b1, w2, b2, wsAcc, N);
  }
  finalize_kernel<<<B, 256, 0, stream>>>(wsAcc, token, wc1, bc1, wc2, bc2, ln_g, ln_b, out);
}